// Round 1
// baseline (1182.278 us; speedup 1.0000x reference)
//
#include <hip/hip_runtime.h>
#include <hip/hip_bf16.h>

#define N_NODES 25000
#define N_EDGES 400000

typedef __attribute__((ext_vector_type(8))) short short8;
typedef __attribute__((ext_vector_type(4))) float f32x4;

__device__ __forceinline__ float silu_f(float x) { return x / (1.0f + __expf(-x)); }

__device__ __forceinline__ short f2bf_s(float x) {
  __hip_bfloat16 h = __float2bfloat16(x);
  return *reinterpret_cast<short*>(&h);
}
__device__ __forceinline__ float bf_s2f(short s) {
  __hip_bfloat16 h = *reinterpret_cast<__hip_bfloat16*>(&s);
  return __bfloat162float(h);
}

// ---------------------------------------------------------------------------
// Edge preprocessing: counting sort by destination row (once per launch,
// amortized over 6 GCL edge passes).
// ---------------------------------------------------------------------------
__global__ __launch_bounds__(256) void k_hist(const int* __restrict__ rows,
                                              int* __restrict__ counts)
{
  int stride = gridDim.x * blockDim.x;
  for (int e = blockIdx.x * blockDim.x + threadIdx.x; e < N_EDGES; e += stride)
    atomicAdd(&counts[rows[e]], 1);
}

__global__ __launch_bounds__(1024) void k_scan(const int* __restrict__ counts,
                                               int* __restrict__ offs,
                                               int* __restrict__ cursor)
{
  __shared__ int buf[1024];
  __shared__ int carry_s;
  const int t = threadIdx.x;
  if (t == 0) carry_s = 0;
  __syncthreads();
  for (int base = 0; base < N_NODES; base += 1024) {
    int i = base + t;
    int x = (i < N_NODES) ? counts[i] : 0;
    buf[t] = x;
    __syncthreads();
    for (int d = 1; d < 1024; d <<= 1) {
      int y = (t >= d) ? buf[t - d] : 0;
      __syncthreads();
      buf[t] += y;
      __syncthreads();
    }
    int incl = buf[t];
    int excl = incl - x;
    int carry = carry_s;
    __syncthreads();
    if (i < N_NODES) {
      offs[i] = carry + excl;
      cursor[i] = carry + excl;
    }
    if (t == 1023) carry_s = carry + incl;
    __syncthreads();
  }
  if (t == 0) offs[N_NODES] = carry_s;
}

__global__ __launch_bounds__(256) void k_scatter(
    const int* __restrict__ rows, const int* __restrict__ cols,
    const float* __restrict__ eatt,
    int* __restrict__ cursor, int* __restrict__ scol, float* __restrict__ sea)
{
  int stride = gridDim.x * blockDim.x;
  for (int e = blockIdx.x * blockDim.x + threadIdx.x; e < N_EDGES; e += stride) {
    int r = rows[e];
    int pos = atomicAdd(&cursor[r], 1);
    scol[pos] = cols[e];
    sea[pos] = eatt[e];
  }
}

// ---------------------------------------------------------------------------
// Embedding: h = silu([h_g0|h_g1] @ Wg1 + bg1) @ Wg2 + bg2
// ---------------------------------------------------------------------------
__global__ __launch_bounds__(256) void k_embed(
    const float* __restrict__ nodes, const float* __restrict__ W_emb, const float* __restrict__ b_emb,
    const float* __restrict__ Wg1, const float* __restrict__ bg1,
    const float* __restrict__ Wg2, const float* __restrict__ bg2,
    float* __restrict__ h)
{
  __shared__ float We[5 * 64];
  __shared__ float W1[128 * 64];
  __shared__ float W2[64 * 64];
  __shared__ float be[64], b1s[64], b2s[64];
  __shared__ __align__(16) float hbuf[4][128];
  __shared__ __align__(16) float tbuf[4][64];

  for (int t = threadIdx.x; t < 128 * 64; t += 256) W1[t] = Wg1[t];
  for (int t = threadIdx.x; t < 64 * 64; t += 256) W2[t] = Wg2[t];
  for (int t = threadIdx.x; t < 5 * 64; t += 256) We[t] = W_emb[t];
  if (threadIdx.x < 64) {
    be[threadIdx.x]  = b_emb[threadIdx.x];
    b1s[threadIdx.x] = bg1[threadIdx.x];
    b2s[threadIdx.x] = bg2[threadIdx.x];
  }
  __syncthreads();

  const int lane = threadIdx.x & 63;
  const int wv = threadIdx.x >> 6;
  float* hb = hbuf[wv];
  float* tb = tbuf[wv];
  const float4* hb4 = (const float4*)hb;
  const float4* tb4 = (const float4*)tb;

  int n0 = blockIdx.x * 32 + wv * 8;
  int n1 = min(n0 + 8, N_NODES);
  for (int n = n0; n < n1; ++n) {
    float x0 = nodes[n * 5 + 0], x1 = nodes[n * 5 + 1],
          x2 = nodes[n * 5 + 2], x3 = nodes[n * 5 + 3],
          x4 = nodes[n * 5 + 4];
    float w0 = We[0 * 64 + lane], w1 = We[1 * 64 + lane], w2 = We[2 * 64 + lane],
          w3 = We[3 * 64 + lane], w4 = We[4 * 64 + lane];
    float base = be[lane] + x4 * w4;
    float s = x0 * w0 + x1 * w1 + x2 * w2 + x3 * w3;
    hb[lane] = base + s;
    hb[64 + lane] = base - s;
    __builtin_amdgcn_wave_barrier();

    float t = b1s[lane];
#pragma unroll
    for (int k4 = 0; k4 < 32; ++k4) {
      float4 hh = hb4[k4];
      t += hh.x * W1[(4 * k4 + 0) * 64 + lane];
      t += hh.y * W1[(4 * k4 + 1) * 64 + lane];
      t += hh.z * W1[(4 * k4 + 2) * 64 + lane];
      t += hh.w * W1[(4 * k4 + 3) * 64 + lane];
    }
    t = silu_f(t);
    __builtin_amdgcn_wave_barrier();
    tb[lane] = t;
    __builtin_amdgcn_wave_barrier();

    float o = b2s[lane];
#pragma unroll
    for (int k4 = 0; k4 < 16; ++k4) {
      float4 tt = tb4[k4];
      o += tt.x * W2[(4 * k4 + 0) * 64 + lane];
      o += tt.y * W2[(4 * k4 + 1) * 64 + lane];
      o += tt.z * W2[(4 * k4 + 2) * 64 + lane];
      o += tt.w * W2[(4 * k4 + 3) * 64 + lane];
    }
    h[n * 64 + lane] = o;
    __builtin_amdgcn_wave_barrier();
  }
}

// ---------------------------------------------------------------------------
// Per-layer node precompute: u = h @ eW1[0:64], v = h @ eW1[64:128]
// ---------------------------------------------------------------------------
__global__ __launch_bounds__(256) void k_node_pre(
    const float* __restrict__ h, const float* __restrict__ eW1,
    float* __restrict__ u, float* __restrict__ v)
{
  const int lane = threadIdx.x & 63;
  const int wv = threadIdx.x >> 6;
  float ar[64], br[64];
#pragma unroll
  for (int k = 0; k < 64; ++k) {
    ar[k] = eW1[k * 64 + lane];
    br[k] = eW1[(64 + k) * 64 + lane];
  }
  __shared__ __align__(16) float hbuf[4][64];
  float* hb = hbuf[wv];
  const float4* hb4 = (const float4*)hb;

  int nw = gridDim.x * 4;
  int wid = blockIdx.x * 4 + wv;
  int per = (N_NODES + nw - 1) / nw;
  int n0 = wid * per, n1 = min(N_NODES, n0 + per);
  for (int n = n0; n < n1; ++n) {
    hb[lane] = h[n * 64 + lane];
    __builtin_amdgcn_wave_barrier();
    float uu = 0.f, vv = 0.f;
#pragma unroll
    for (int k4 = 0; k4 < 16; ++k4) {
      float4 hh = hb4[k4];
      uu += hh.x * ar[4 * k4 + 0]; vv += hh.x * br[4 * k4 + 0];
      uu += hh.y * ar[4 * k4 + 1]; vv += hh.y * br[4 * k4 + 1];
      uu += hh.z * ar[4 * k4 + 2]; vv += hh.z * br[4 * k4 + 2];
      uu += hh.w * ar[4 * k4 + 3]; vv += hh.w * br[4 * k4 + 3];
    }
    u[n * 64 + lane] = uu;
    v[n * 64 + lane] = vv;
    __builtin_amdgcn_wave_barrier();
  }
}

// ---------------------------------------------------------------------------
// Fused edge kernel, sorted-by-row, wave-per-row, NO atomics.
// Per wave: row r, edges [offs[r], offs[r+1]) in tiles of 16:
//   phase1: t = silu(u[r]+v[c]+ea*w+b1)  (lane = feature) -> LDS [feat][edge]
//   phase2: e_pre = t @ W2 via split-bf16 MFMA (hi/lo, 3 products ~ fp32)
//   epilogue: e = silu(e_pre + b2); masked in-register sum over tile edges
// End of row: cross-quad shuffle reduce, one coalesced 256B store to agg[r].
// A-frag layout: A[m=lane&15][k=quad*8+j]; C/D: row=quad*4+reg, col=nt*16+n16.
// ---------------------------------------------------------------------------
__global__ __launch_bounds__(256) void k_edge(
    const float* __restrict__ u, const float* __restrict__ v,
    const int* __restrict__ scol, const float* __restrict__ sea,
    const int* __restrict__ offs,
    const float* __restrict__ wea, const float* __restrict__ eb1,
    const float* __restrict__ W2, const float* __restrict__ eb2,
    float* __restrict__ agg)
{
  const int lane = threadIdx.x & 63;
  const int wv = threadIdx.x >> 6;
  const int n16 = lane & 15;
  const int quad = lane >> 4;

  // B fragments (W2 columns), split hi/lo, resident in VGPRs.
  short8 Whi[2][4], Wlo[2][4];
#pragma unroll
  for (int s = 0; s < 2; ++s) {
#pragma unroll
    for (int nt = 0; nt < 4; ++nt) {
#pragma unroll
      for (int j = 0; j < 8; ++j) {
        float w2v = W2[(s * 32 + quad * 8 + j) * 64 + nt * 16 + n16];
        short hi = f2bf_s(w2v);
        Whi[s][nt][j] = hi;
        Wlo[s][nt][j] = f2bf_s(w2v - bf_s2f(hi));
      }
    }
  }
  float we = wea[lane];
  float b1v = eb1[lane];
  float b2v[4];
#pragma unroll
  for (int nt = 0; nt < 4; ++nt) b2v[nt] = eb2[nt * 16 + n16];

  __shared__ float Tl[4][64 * 17];   // [feat][edge], pad 17: <=2-way conflicts
  float* T = Tl[wv];

  const int nw = gridDim.x * 4;
  for (int r = blockIdx.x * 4 + wv; r < N_NODES; r += nw) {
    int e_beg = offs[r], e_end = offs[r + 1];
    float ub = u[r * 64 + lane] + b1v;     // loaded ONCE per row
    float asum[4] = {0.f, 0.f, 0.f, 0.f};

    for (int base = e_beg; base < e_end; base += 16) {
      int cnt = min(16, e_end - base);
      int c16 = 0; float ea16 = 0.f;
      if (lane < cnt) { c16 = scol[base + lane]; ea16 = sea[base + lane]; }

      // phase 1: up to 16 edges, lane = feature
#pragma unroll 4
      for (int e = 0; e < 16; ++e) {
        if (e < cnt) {
          int c = __shfl(c16, e);
          float ea = __shfl(ea16, e);
          T[lane * 17 + e] = silu_f(ub + v[c * 64 + lane] + ea * we);
        } else {
          T[lane * 17 + e] = 0.f;
        }
      }
      __builtin_amdgcn_wave_barrier();

      f32x4 acc[4] = {};
#pragma unroll
      for (int s = 0; s < 2; ++s) {
        short8 ahi, alo;
#pragma unroll
        for (int j = 0; j < 8; ++j) {
          float tv = T[(s * 32 + quad * 8 + j) * 17 + n16];
          short hi = f2bf_s(tv);
          ahi[j] = hi;
          alo[j] = f2bf_s(tv - bf_s2f(hi));
        }
#pragma unroll
        for (int nt = 0; nt < 4; ++nt) {
          acc[nt] = __builtin_amdgcn_mfma_f32_16x16x32_bf16(ahi, Whi[s][nt], acc[nt], 0, 0, 0);
          acc[nt] = __builtin_amdgcn_mfma_f32_16x16x32_bf16(ahi, Wlo[s][nt], acc[nt], 0, 0, 0);
          acc[nt] = __builtin_amdgcn_mfma_f32_16x16x32_bf16(alo, Whi[s][nt], acc[nt], 0, 0, 0);
        }
      }
      __builtin_amdgcn_wave_barrier();

      // epilogue: silu + masked in-register reduce over this tile's edges.
      // D row = quad*4+reg (edge within tile), col = nt*16+n16 (feature).
#pragma unroll
      for (int reg = 0; reg < 4; ++reg) {
        bool val = (quad * 4 + reg) < cnt;
#pragma unroll
        for (int nt = 0; nt < 4; ++nt) {
          float ev = silu_f(acc[nt][reg] + b2v[nt]);
          asum[nt] += val ? ev : 0.f;
        }
      }
      __builtin_amdgcn_wave_barrier();
    }

    // cross-quad reduce: lanes {n16, 16+n16, 32+n16, 48+n16} hold partials
    // of feature nt*16+n16 for their edge-quad.
#pragma unroll
    for (int nt = 0; nt < 4; ++nt) {
      asum[nt] += __shfl_xor(asum[nt], 16);
      asum[nt] += __shfl_xor(asum[nt], 32);
    }
    // lane = quad*16+n16 stores feature lane => pick asum[quad]
    float o = asum[0];
    o = (quad == 1) ? asum[1] : o;
    o = (quad == 2) ? asum[2] : o;
    o = (quad == 3) ? asum[3] : o;
    agg[r * 64 + lane] = o;   // degree-0 rows store 0 (no memset needed)
  }
}

// ---------------------------------------------------------------------------
// Per-layer node MLP: h = silu(h@nW1[0:64] + agg@nW1[64:128] + nb1) @ nW2 + nb2
// ---------------------------------------------------------------------------
__global__ __launch_bounds__(256, 2) void k_node_post(
    float* __restrict__ h, const float* __restrict__ agg,
    const float* __restrict__ nW1, const float* __restrict__ nb1,
    const float* __restrict__ nW2, const float* __restrict__ nb2)
{
  const int lane = threadIdx.x & 63;
  const int wv = threadIdx.x >> 6;
  float ar[64], br[64], wr[64];
#pragma unroll
  for (int k = 0; k < 64; ++k) {
    ar[k] = nW1[k * 64 + lane];
    br[k] = nW1[(64 + k) * 64 + lane];
    wr[k] = nW2[k * 64 + lane];
  }
  float b1v = nb1[lane], b2v = nb2[lane];
  __shared__ __align__(16) float hbuf[4][64];
  __shared__ __align__(16) float abuf[4][64];
  __shared__ __align__(16) float tbuf[4][64];
  float* hb = hbuf[wv]; float* ab = abuf[wv]; float* tb = tbuf[wv];
  const float4* hb4 = (const float4*)hb;
  const float4* ab4 = (const float4*)ab;
  const float4* tb4 = (const float4*)tb;

  int nw = gridDim.x * 4;
  int wid = blockIdx.x * 4 + wv;
  int per = (N_NODES + nw - 1) / nw;
  int n0 = wid * per, n1 = min(N_NODES, n0 + per);
  for (int n = n0; n < n1; ++n) {
    hb[lane] = h[n * 64 + lane];
    ab[lane] = agg[n * 64 + lane];
    __builtin_amdgcn_wave_barrier();
    float t = b1v;
#pragma unroll
    for (int k4 = 0; k4 < 16; ++k4) {
      float4 hh = hb4[k4];
      float4 aa = ab4[k4];
      t += hh.x * ar[4 * k4 + 0] + aa.x * br[4 * k4 + 0];
      t += hh.y * ar[4 * k4 + 1] + aa.y * br[4 * k4 + 1];
      t += hh.z * ar[4 * k4 + 2] + aa.z * br[4 * k4 + 2];
      t += hh.w * ar[4 * k4 + 3] + aa.w * br[4 * k4 + 3];
    }
    t = silu_f(t);
    __builtin_amdgcn_wave_barrier();
    tb[lane] = t;
    __builtin_amdgcn_wave_barrier();
    float o = b2v;
#pragma unroll
    for (int k4 = 0; k4 < 16; ++k4) {
      float4 tt = tb4[k4];
      o += tt.x * wr[4 * k4 + 0];
      o += tt.y * wr[4 * k4 + 1];
      o += tt.z * wr[4 * k4 + 2];
      o += tt.w * wr[4 * k4 + 3];
    }
    h[n * 64 + lane] = o;
    __builtin_amdgcn_wave_barrier();
  }
}

// ---------------------------------------------------------------------------
// Final node MLP: out = silu(concat(h,agg) @ dnW1 + dnb1) @ dnW2 + dnb2, (N,4)
// ---------------------------------------------------------------------------
__global__ __launch_bounds__(256, 2) void k_node_final(
    const float* __restrict__ h, const float* __restrict__ agg,
    const float* __restrict__ dnW1, const float* __restrict__ dnb1,
    const float* __restrict__ dnW2, const float* __restrict__ dnb2,
    float* __restrict__ out)
{
  const int lane = threadIdx.x & 63;
  const int wv = threadIdx.x >> 6;
  float ar[64], br[64], wr[64];
#pragma unroll
  for (int k = 0; k < 64; ++k) {
    ar[k] = dnW1[k * 64 + lane];
    br[k] = dnW1[(64 + k) * 64 + lane];
    wr[k] = dnW2[k * 4 + (lane & 3)];
  }
  float b1v = dnb1[lane];
  float b2v = dnb2[lane & 3];
  __shared__ __align__(16) float hbuf[4][64];
  __shared__ __align__(16) float abuf[4][64];
  __shared__ __align__(16) float tbuf[4][64];
  float* hb = hbuf[wv]; float* ab = abuf[wv]; float* tb = tbuf[wv];
  const float4* hb4 = (const float4*)hb;
  const float4* ab4 = (const float4*)ab;
  const float4* tb4 = (const float4*)tb;

  int nw = gridDim.x * 4;
  int wid = blockIdx.x * 4 + wv;
  int per = (N_NODES + nw - 1) / nw;
  int n0 = wid * per, n1 = min(N_NODES, n0 + per);
  for (int n = n0; n < n1; ++n) {
    hb[lane] = h[n * 64 + lane];
    ab[lane] = agg[n * 64 + lane];
    __builtin_amdgcn_wave_barrier();
    float t = b1v;
#pragma unroll
    for (int k4 = 0; k4 < 16; ++k4) {
      float4 hh = hb4[k4];
      float4 aa = ab4[k4];
      t += hh.x * ar[4 * k4 + 0] + aa.x * br[4 * k4 + 0];
      t += hh.y * ar[4 * k4 + 1] + aa.y * br[4 * k4 + 1];
      t += hh.z * ar[4 * k4 + 2] + aa.z * br[4 * k4 + 2];
      t += hh.w * ar[4 * k4 + 3] + aa.w * br[4 * k4 + 3];
    }
    t = silu_f(t);
    __builtin_amdgcn_wave_barrier();
    tb[lane] = t;
    __builtin_amdgcn_wave_barrier();
    float o = b2v;
#pragma unroll
    for (int k4 = 0; k4 < 16; ++k4) {
      float4 tt = tb4[k4];
      o += tt.x * wr[4 * k4 + 0];
      o += tt.y * wr[4 * k4 + 1];
      o += tt.z * wr[4 * k4 + 2];
      o += tt.w * wr[4 * k4 + 3];
    }
    if (lane < 4) out[n * 4 + lane] = o;
    __builtin_amdgcn_wave_barrier();
  }
}

extern "C" void kernel_launch(void* const* d_in, const int* in_sizes, int n_in,
                              void* d_out, int out_size, void* d_ws, size_t ws_size,
                              hipStream_t stream)
{
  const float* nodes = (const float*)d_in[0];
  const int*   edges = (const int*)d_in[1];
  const float* eatt  = (const float*)d_in[2];
  const float* W_emb = (const float*)d_in[3];
  const float* b_emb = (const float*)d_in[4];
  const float* Wg1   = (const float*)d_in[5];
  const float* bg1   = (const float*)d_in[6];
  const float* Wg2   = (const float*)d_in[7];
  const float* bg2   = (const float*)d_in[8];
  const float* eW1   = (const float*)d_in[9];
  const float* eb1   = (const float*)d_in[10];
  const float* eW2   = (const float*)d_in[11];
  const float* eb2   = (const float*)d_in[12];
  const float* nW1   = (const float*)d_in[13];
  const float* nb1   = (const float*)d_in[14];
  const float* nW2   = (const float*)d_in[15];
  const float* nb2   = (const float*)d_in[16];
  const float* deW1  = (const float*)d_in[17];
  const float* deb1  = (const float*)d_in[18];
  const float* deW2  = (const float*)d_in[19];
  const float* deb2  = (const float*)d_in[20];
  const float* dnW1  = (const float*)d_in[21];
  const float* dnb1  = (const float*)d_in[22];
  const float* dnW2  = (const float*)d_in[23];
  const float* dnb2  = (const float*)d_in[24];
  float* out = (float*)d_out;

  // workspace: h,u,v,agg (4 x 6.4MB) + counts(25000) + offs(25001) +
  // cursor(25000) + scol(400000) + sea(400000)  ~= 29.0 MB total
  float* h   = (float*)d_ws;
  float* u   = h + N_NODES * 64;
  float* v   = u + N_NODES * 64;
  float* agg = v + N_NODES * 64;
  int* counts = (int*)(agg + N_NODES * 64);
  int* offs   = counts + N_NODES;
  int* cursor = offs + N_NODES + 1;
  int* scol   = cursor + N_NODES;
  float* sea  = (float*)(scol + N_EDGES);

  const int* rows = edges;
  const int* cols = edges + N_EDGES;

  // --- one-time edge sort by destination row (graph static across layers) ---
  hipMemsetAsync(counts, 0, N_NODES * sizeof(int), stream);
  k_hist<<<1024, 256, 0, stream>>>(rows, counts);
  k_scan<<<1, 1024, 0, stream>>>(counts, offs, cursor);
  k_scatter<<<1024, 256, 0, stream>>>(rows, cols, eatt, cursor, scol, sea);

  k_embed<<<(N_NODES + 31) / 32, 256, 0, stream>>>(nodes, W_emb, b_emb, Wg1, bg1, Wg2, bg2, h);

  for (int i = 0; i < 5; ++i) {
    const float* W1i = eW1 + i * 129 * 64;
    k_node_pre<<<1024, 256, 0, stream>>>(h, W1i, u, v);
    k_edge<<<1024, 256, 0, stream>>>(u, v, scol, sea, offs, W1i + 128 * 64,
                                     eb1 + i * 64, eW2 + i * 64 * 64, eb2 + i * 64, agg);
    k_node_post<<<1024, 256, 0, stream>>>(h, agg, nW1 + i * 128 * 64, nb1 + i * 64,
                                          nW2 + i * 64 * 64, nb2 + i * 64);
  }
  // decoder GCL
  k_node_pre<<<1024, 256, 0, stream>>>(h, deW1, u, v);
  k_edge<<<1024, 256, 0, stream>>>(u, v, scol, sea, offs, deW1 + 128 * 64,
                                   deb1, deW2, deb2, agg);
  k_node_final<<<1024, 256, 0, stream>>>(h, agg, dnW1, dnb1, dnW2, dnb2, out);
}

// Round 2
// 783.313 us; speedup vs baseline: 1.5093x; 1.5093x over previous
//
#include <hip/hip_runtime.h>
#include <hip/hip_bf16.h>

#define N_NODES 25000
#define N_EDGES 400000
#define NB_SCAN ((N_NODES + 255) / 256)   // 98

typedef __attribute__((ext_vector_type(8))) short short8;
typedef __attribute__((ext_vector_type(4))) float f32x4;

__device__ __forceinline__ float silu_f(float x) { return x / (1.0f + __expf(-x)); }

__device__ __forceinline__ short f2bf_s(float x) {
  __hip_bfloat16 h = __float2bfloat16(x);
  return *reinterpret_cast<short*>(&h);
}
__device__ __forceinline__ float bf_s2f(short s) {
  __hip_bfloat16 h = *reinterpret_cast<__hip_bfloat16*>(&s);
  return __bfloat162float(h);
}

// ---------------------------------------------------------------------------
// Edge preprocessing: counting sort by destination row (once per launch).
// Hierarchical scan (3 micro-kernels) replaces the slow 1-block scan.
// ---------------------------------------------------------------------------
__global__ __launch_bounds__(256) void k_hist(const int* __restrict__ rows,
                                              int* __restrict__ counts)
{
  int stride = gridDim.x * blockDim.x;
  for (int e = blockIdx.x * blockDim.x + threadIdx.x; e < N_EDGES; e += stride)
    atomicAdd(&counts[rows[e]], 1);
}

__global__ __launch_bounds__(256) void k_scanA(const int* __restrict__ counts,
                                               int* __restrict__ bsum)
{
  __shared__ int sd[256];
  int t = threadIdx.x;
  int i = blockIdx.x * 256 + t;
  int x = (i < N_NODES) ? counts[i] : 0;
  sd[t] = x; __syncthreads();
  for (int d = 128; d > 0; d >>= 1) { if (t < d) sd[t] += sd[t + d]; __syncthreads(); }
  if (t == 0) bsum[blockIdx.x] = sd[0];
}

__global__ __launch_bounds__(128) void k_scanB(const int* __restrict__ bsum,
                                               int* __restrict__ boffs)
{
  __shared__ int buf[128];
  int t = threadIdx.x;
  int x = (t < NB_SCAN) ? bsum[t] : 0;
  buf[t] = x; __syncthreads();
  for (int d = 1; d < 128; d <<= 1) {
    int y = (t >= d) ? buf[t - d] : 0;
    __syncthreads();
    buf[t] += y;
    __syncthreads();
  }
  if (t < NB_SCAN) boffs[t] = buf[t] - x;   // exclusive block offsets
}

__global__ __launch_bounds__(256) void k_scanC(const int* __restrict__ counts,
                                               const int* __restrict__ boffs,
                                               int* __restrict__ cursor)
{
  __shared__ int buf[256];
  int t = threadIdx.x;
  int i = blockIdx.x * 256 + t;
  int x = (i < N_NODES) ? counts[i] : 0;
  buf[t] = x; __syncthreads();
  for (int d = 1; d < 256; d <<= 1) {
    int y = (t >= d) ? buf[t - d] : 0;
    __syncthreads();
    buf[t] += y;
    __syncthreads();
  }
  if (i < N_NODES) cursor[i] = boffs[blockIdx.x] + buf[t] - x;
}

__global__ __launch_bounds__(256) void k_scatter(
    const int* __restrict__ rows, const int* __restrict__ cols,
    const float* __restrict__ eatt, int* __restrict__ cursor,
    int* __restrict__ srow, int* __restrict__ scol, float* __restrict__ sea)
{
  int stride = gridDim.x * blockDim.x;
  for (int e = blockIdx.x * blockDim.x + threadIdx.x; e < N_EDGES; e += stride) {
    int r = rows[e];
    int pos = atomicAdd(&cursor[r], 1);
    srow[pos] = r;
    scol[pos] = cols[e];
    sea[pos] = eatt[e];
  }
}

// ---------------------------------------------------------------------------
// Embedding: h = silu([h_g0|h_g1] @ Wg1 + bg1) @ Wg2 + bg2
// ---------------------------------------------------------------------------
__global__ __launch_bounds__(256) void k_embed(
    const float* __restrict__ nodes, const float* __restrict__ W_emb, const float* __restrict__ b_emb,
    const float* __restrict__ Wg1, const float* __restrict__ bg1,
    const float* __restrict__ Wg2, const float* __restrict__ bg2,
    float* __restrict__ h)
{
  __shared__ float We[5 * 64];
  __shared__ float W1[128 * 64];
  __shared__ float W2[64 * 64];
  __shared__ float be[64], b1s[64], b2s[64];
  __shared__ __align__(16) float hbuf[4][128];
  __shared__ __align__(16) float tbuf[4][64];

  for (int t = threadIdx.x; t < 128 * 64; t += 256) W1[t] = Wg1[t];
  for (int t = threadIdx.x; t < 64 * 64; t += 256) W2[t] = Wg2[t];
  for (int t = threadIdx.x; t < 5 * 64; t += 256) We[t] = W_emb[t];
  if (threadIdx.x < 64) {
    be[threadIdx.x]  = b_emb[threadIdx.x];
    b1s[threadIdx.x] = bg1[threadIdx.x];
    b2s[threadIdx.x] = bg2[threadIdx.x];
  }
  __syncthreads();

  const int lane = threadIdx.x & 63;
  const int wv = threadIdx.x >> 6;
  float* hb = hbuf[wv];
  float* tb = tbuf[wv];
  const float4* hb4 = (const float4*)hb;
  const float4* tb4 = (const float4*)tb;

  int n0 = blockIdx.x * 32 + wv * 8;
  int n1 = min(n0 + 8, N_NODES);
  for (int n = n0; n < n1; ++n) {
    float x0 = nodes[n * 5 + 0], x1 = nodes[n * 5 + 1],
          x2 = nodes[n * 5 + 2], x3 = nodes[n * 5 + 3],
          x4 = nodes[n * 5 + 4];
    float w0 = We[0 * 64 + lane], w1 = We[1 * 64 + lane], w2 = We[2 * 64 + lane],
          w3 = We[3 * 64 + lane], w4 = We[4 * 64 + lane];
    float base = be[lane] + x4 * w4;
    float s = x0 * w0 + x1 * w1 + x2 * w2 + x3 * w3;
    hb[lane] = base + s;
    hb[64 + lane] = base - s;
    __builtin_amdgcn_wave_barrier();

    float t = b1s[lane];
#pragma unroll
    for (int k4 = 0; k4 < 32; ++k4) {
      float4 hh = hb4[k4];
      t += hh.x * W1[(4 * k4 + 0) * 64 + lane];
      t += hh.y * W1[(4 * k4 + 1) * 64 + lane];
      t += hh.z * W1[(4 * k4 + 2) * 64 + lane];
      t += hh.w * W1[(4 * k4 + 3) * 64 + lane];
    }
    t = silu_f(t);
    __builtin_amdgcn_wave_barrier();
    tb[lane] = t;
    __builtin_amdgcn_wave_barrier();

    float o = b2s[lane];
#pragma unroll
    for (int k4 = 0; k4 < 16; ++k4) {
      float4 tt = tb4[k4];
      o += tt.x * W2[(4 * k4 + 0) * 64 + lane];
      o += tt.y * W2[(4 * k4 + 1) * 64 + lane];
      o += tt.z * W2[(4 * k4 + 2) * 64 + lane];
      o += tt.w * W2[(4 * k4 + 3) * 64 + lane];
    }
    h[n * 64 + lane] = o;
    __builtin_amdgcn_wave_barrier();
  }
}

// ---------------------------------------------------------------------------
// Per-layer node precompute: u = h @ eW1[0:64], v = h @ eW1[64:128].
// Also zero-inits agg (replaces hipMemsetAsync; k_edge stores/atomics need 0).
// ---------------------------------------------------------------------------
__global__ __launch_bounds__(256) void k_node_pre(
    const float* __restrict__ h, const float* __restrict__ eW1,
    float* __restrict__ u, float* __restrict__ v, float* __restrict__ agg)
{
  const int lane = threadIdx.x & 63;
  const int wv = threadIdx.x >> 6;
  float ar[64], br[64];
#pragma unroll
  for (int k = 0; k < 64; ++k) {
    ar[k] = eW1[k * 64 + lane];
    br[k] = eW1[(64 + k) * 64 + lane];
  }
  __shared__ __align__(16) float hbuf[4][64];
  float* hb = hbuf[wv];
  const float4* hb4 = (const float4*)hb;

  int nw = gridDim.x * 4;
  int wid = blockIdx.x * 4 + wv;
  int per = (N_NODES + nw - 1) / nw;
  int n0 = wid * per, n1 = min(N_NODES, n0 + per);
  for (int n = n0; n < n1; ++n) {
    hb[lane] = h[n * 64 + lane];
    agg[n * 64 + lane] = 0.f;
    __builtin_amdgcn_wave_barrier();
    float uu = 0.f, vv = 0.f;
#pragma unroll
    for (int k4 = 0; k4 < 16; ++k4) {
      float4 hh = hb4[k4];
      uu += hh.x * ar[4 * k4 + 0]; vv += hh.x * br[4 * k4 + 0];
      uu += hh.y * ar[4 * k4 + 1]; vv += hh.y * br[4 * k4 + 1];
      uu += hh.z * ar[4 * k4 + 2]; vv += hh.z * br[4 * k4 + 2];
      uu += hh.w * ar[4 * k4 + 3]; vv += hh.w * br[4 * k4 + 3];
    }
    u[n * 64 + lane] = uu;
    v[n * 64 + lane] = vv;
    __builtin_amdgcn_wave_barrier();
  }
}

// ---------------------------------------------------------------------------
// Fused edge kernel over SORTED edges, dense 16-edge tiles (exactly 25000),
// contiguous 5-tile range per wave, running segmented reduction epilogue.
//   phase1: t = silu(u[r]+v[c]+ea*w+b1)  (lane = feature) -> LDS [feat][edge]
//   phase2: e_pre = t @ W2 via split-bf16 MFMA (hi/lo, 3 products ~ fp32)
//   epilogue: rows sorted => row-change boundaries = wave-uniform ballot;
//     accumulate per-lane partials; flush one coalesced row-store on change.
//     Only first/final flush of the wave's range may share a row with a
//     neighboring wave -> unsafeAtomicAdd for those, plain store otherwise.
// A-frag layout: A[m=lane&15][k=quad*8+j]; C/D: row=quad*4+reg, col=nt*16+n16.
// ---------------------------------------------------------------------------
__global__ __launch_bounds__(256) void k_edge(
    const float* __restrict__ u, const float* __restrict__ v,
    const int* __restrict__ srow, const int* __restrict__ scol,
    const float* __restrict__ sea,
    const float* __restrict__ wea, const float* __restrict__ eb1,
    const float* __restrict__ W2, const float* __restrict__ eb2,
    float* __restrict__ agg)
{
  const int lane = threadIdx.x & 63;
  const int wv = threadIdx.x >> 6;
  const int n16 = lane & 15;
  const int quad = lane >> 4;

  // B fragments (W2 columns), split hi/lo, resident in VGPRs.
  short8 Whi[2][4], Wlo[2][4];
#pragma unroll
  for (int s = 0; s < 2; ++s) {
#pragma unroll
    for (int nt = 0; nt < 4; ++nt) {
#pragma unroll
      for (int j = 0; j < 8; ++j) {
        float w2v = W2[(s * 32 + quad * 8 + j) * 64 + nt * 16 + n16];
        short hi = f2bf_s(w2v);
        Whi[s][nt][j] = hi;
        Wlo[s][nt][j] = f2bf_s(w2v - bf_s2f(hi));
      }
    }
  }
  float we = wea[lane];
  float b1v = eb1[lane];
  float b2v[4];
#pragma unroll
  for (int nt = 0; nt < 4; ++nt) b2v[nt] = eb2[nt * 16 + n16];

  __shared__ float Tl[4][64 * 17];   // [feat][edge], pad 17: <=2-way conflicts
  float* T = Tl[wv];

  // grid = 1250 blocks * 4 waves = 5000 waves; 5 tiles each (25000 exact).
  const int wid = blockIdx.x * 4 + wv;
  const int tile0 = wid * 5, tile1 = tile0 + 5;

  int cur_row = -1;
  bool first_atomic = true;
  float asum[4] = {0.f, 0.f, 0.f, 0.f};

  auto reduce_pick = [&](float a0, float a1, float a2, float a3) -> float {
    a0 += __shfl_xor(a0, 16); a0 += __shfl_xor(a0, 32);
    a1 += __shfl_xor(a1, 16); a1 += __shfl_xor(a1, 32);
    a2 += __shfl_xor(a2, 16); a2 += __shfl_xor(a2, 32);
    a3 += __shfl_xor(a3, 16); a3 += __shfl_xor(a3, 32);
    float o = a0;
    o = (quad == 1) ? a1 : o;
    o = (quad == 2) ? a2 : o;
    o = (quad == 3) ? a3 : o;
    return o;
  };

  for (int tile = tile0; tile < tile1; ++tile) {
    int e0 = tile * 16;
    int r16a = srow[e0 + n16];
    int c16a = scol[e0 + n16];
    float ea16 = sea[e0 + n16];

    // phase 1: 16 edges, lane = feature (dense, no masking)
#pragma unroll 4
    for (int e = 0; e < 16; ++e) {
      int r = __shfl(r16a, e);
      int c = __shfl(c16a, e);
      float ea = __shfl(ea16, e);
      float tt = u[r * 64 + lane] + v[c * 64 + lane] + ea * we + b1v;
      T[lane * 17 + e] = silu_f(tt);
    }
    __builtin_amdgcn_wave_barrier();

    f32x4 acc[4] = {};
#pragma unroll
    for (int s = 0; s < 2; ++s) {
      short8 ahi, alo;
#pragma unroll
      for (int j = 0; j < 8; ++j) {
        float tv = T[(s * 32 + quad * 8 + j) * 17 + n16];
        short hi = f2bf_s(tv);
        ahi[j] = hi;
        alo[j] = f2bf_s(tv - bf_s2f(hi));
      }
#pragma unroll
      for (int nt = 0; nt < 4; ++nt) {
        acc[nt] = __builtin_amdgcn_mfma_f32_16x16x32_bf16(ahi, Whi[s][nt], acc[nt], 0, 0, 0);
        acc[nt] = __builtin_amdgcn_mfma_f32_16x16x32_bf16(ahi, Wlo[s][nt], acc[nt], 0, 0, 0);
        acc[nt] = __builtin_amdgcn_mfma_f32_16x16x32_bf16(alo, Whi[s][nt], acc[nt], 0, 0, 0);
      }
    }
    __builtin_amdgcn_wave_barrier();

    // epilogue: silu, then running segmented reduce by row.
    float ev[4][4];   // [reg][nt], all indices compile-time (stays in VGPRs)
#pragma unroll
    for (int reg = 0; reg < 4; ++reg)
#pragma unroll
      for (int nt = 0; nt < 4; ++nt)
        ev[reg][nt] = silu_f(acc[nt][reg] + b2v[nt]);

    // wave-uniform row-boundary mask over the 16 slots
    int rup = __shfl_up(r16a, 1);
    bool nf = (lane < 16) && ((lane == 0) ? (r16a != cur_row) : (r16a != rup));
    unsigned mask = (unsigned)(__ballot(nf) & 0xFFFFull);

    int s = 0;
    while (s < 16) {
      if ((mask >> s) & 1u) {
        if (cur_row >= 0) {
          float o = reduce_pick(asum[0], asum[1], asum[2], asum[3]);
          if (first_atomic) { unsafeAtomicAdd(&agg[cur_row * 64 + lane], o); first_atomic = false; }
          else agg[cur_row * 64 + lane] = o;
        }
        asum[0] = asum[1] = asum[2] = asum[3] = 0.f;
        cur_row = __shfl(r16a, s);
      }
      unsigned rem = mask & ~((2u << s) - 1u);   // boundaries strictly after s
      int e = rem ? (__ffs(rem) - 1) : 16;
#pragma unroll
      for (int reg = 0; reg < 4; ++reg) {
        int m = quad * 4 + reg;
        bool in = (m >= s) && (m < e);
        asum[0] += in ? ev[reg][0] : 0.f;
        asum[1] += in ? ev[reg][1] : 0.f;
        asum[2] += in ? ev[reg][2] : 0.f;
        asum[3] += in ? ev[reg][3] : 0.f;
      }
      s = e;
    }
    __builtin_amdgcn_wave_barrier();
  }

  // final flush: row may continue into the next wave's range -> atomic
  if (cur_row >= 0) {
    float o = reduce_pick(asum[0], asum[1], asum[2], asum[3]);
    unsafeAtomicAdd(&agg[cur_row * 64 + lane], o);
  }
}

// ---------------------------------------------------------------------------
// Per-layer node MLP: h = silu(h@nW1[0:64] + agg@nW1[64:128] + nb1) @ nW2 + nb2
// ---------------------------------------------------------------------------
__global__ __launch_bounds__(256, 2) void k_node_post(
    float* __restrict__ h, const float* __restrict__ agg,
    const float* __restrict__ nW1, const float* __restrict__ nb1,
    const float* __restrict__ nW2, const float* __restrict__ nb2)
{
  const int lane = threadIdx.x & 63;
  const int wv = threadIdx.x >> 6;
  float ar[64], br[64], wr[64];
#pragma unroll
  for (int k = 0; k < 64; ++k) {
    ar[k] = nW1[k * 64 + lane];
    br[k] = nW1[(64 + k) * 64 + lane];
    wr[k] = nW2[k * 64 + lane];
  }
  float b1v = nb1[lane], b2v = nb2[lane];
  __shared__ __align__(16) float hbuf[4][64];
  __shared__ __align__(16) float abuf[4][64];
  __shared__ __align__(16) float tbuf[4][64];
  float* hb = hbuf[wv]; float* ab = abuf[wv]; float* tb = tbuf[wv];
  const float4* hb4 = (const float4*)hb;
  const float4* ab4 = (const float4*)ab;
  const float4* tb4 = (const float4*)tb;

  int nw = gridDim.x * 4;
  int wid = blockIdx.x * 4 + wv;
  int per = (N_NODES + nw - 1) / nw;
  int n0 = wid * per, n1 = min(N_NODES, n0 + per);
  for (int n = n0; n < n1; ++n) {
    hb[lane] = h[n * 64 + lane];
    ab[lane] = agg[n * 64 + lane];
    __builtin_amdgcn_wave_barrier();
    float t = b1v;
#pragma unroll
    for (int k4 = 0; k4 < 16; ++k4) {
      float4 hh = hb4[k4];
      float4 aa = ab4[k4];
      t += hh.x * ar[4 * k4 + 0] + aa.x * br[4 * k4 + 0];
      t += hh.y * ar[4 * k4 + 1] + aa.y * br[4 * k4 + 1];
      t += hh.z * ar[4 * k4 + 2] + aa.z * br[4 * k4 + 2];
      t += hh.w * ar[4 * k4 + 3] + aa.w * br[4 * k4 + 3];
    }
    t = silu_f(t);
    __builtin_amdgcn_wave_barrier();
    tb[lane] = t;
    __builtin_amdgcn_wave_barrier();
    float o = b2v;
#pragma unroll
    for (int k4 = 0; k4 < 16; ++k4) {
      float4 tt = tb4[k4];
      o += tt.x * wr[4 * k4 + 0];
      o += tt.y * wr[4 * k4 + 1];
      o += tt.z * wr[4 * k4 + 2];
      o += tt.w * wr[4 * k4 + 3];
    }
    h[n * 64 + lane] = o;
    __builtin_amdgcn_wave_barrier();
  }
}

// ---------------------------------------------------------------------------
// Final node MLP: out = silu(concat(h,agg) @ dnW1 + dnb1) @ dnW2 + dnb2, (N,4)
// ---------------------------------------------------------------------------
__global__ __launch_bounds__(256, 2) void k_node_final(
    const float* __restrict__ h, const float* __restrict__ agg,
    const float* __restrict__ dnW1, const float* __restrict__ dnb1,
    const float* __restrict__ dnW2, const float* __restrict__ dnb2,
    float* __restrict__ out)
{
  const int lane = threadIdx.x & 63;
  const int wv = threadIdx.x >> 6;
  float ar[64], br[64], wr[64];
#pragma unroll
  for (int k = 0; k < 64; ++k) {
    ar[k] = dnW1[k * 64 + lane];
    br[k] = dnW1[(64 + k) * 64 + lane];
    wr[k] = dnW2[k * 4 + (lane & 3)];
  }
  float b1v = dnb1[lane];
  float b2v = dnb2[lane & 3];
  __shared__ __align__(16) float hbuf[4][64];
  __shared__ __align__(16) float abuf[4][64];
  __shared__ __align__(16) float tbuf[4][64];
  float* hb = hbuf[wv]; float* ab = abuf[wv]; float* tb = tbuf[wv];
  const float4* hb4 = (const float4*)hb;
  const float4* ab4 = (const float4*)ab;
  const float4* tb4 = (const float4*)tb;

  int nw = gridDim.x * 4;
  int wid = blockIdx.x * 4 + wv;
  int per = (N_NODES + nw - 1) / nw;
  int n0 = wid * per, n1 = min(N_NODES, n0 + per);
  for (int n = n0; n < n1; ++n) {
    hb[lane] = h[n * 64 + lane];
    ab[lane] = agg[n * 64 + lane];
    __builtin_amdgcn_wave_barrier();
    float t = b1v;
#pragma unroll
    for (int k4 = 0; k4 < 16; ++k4) {
      float4 hh = hb4[k4];
      float4 aa = ab4[k4];
      t += hh.x * ar[4 * k4 + 0] + aa.x * br[4 * k4 + 0];
      t += hh.y * ar[4 * k4 + 1] + aa.y * br[4 * k4 + 1];
      t += hh.z * ar[4 * k4 + 2] + aa.z * br[4 * k4 + 2];
      t += hh.w * ar[4 * k4 + 3] + aa.w * br[4 * k4 + 3];
    }
    t = silu_f(t);
    __builtin_amdgcn_wave_barrier();
    tb[lane] = t;
    __builtin_amdgcn_wave_barrier();
    float o = b2v;
#pragma unroll
    for (int k4 = 0; k4 < 16; ++k4) {
      float4 tt = tb4[k4];
      o += tt.x * wr[4 * k4 + 0];
      o += tt.y * wr[4 * k4 + 1];
      o += tt.z * wr[4 * k4 + 2];
      o += tt.w * wr[4 * k4 + 3];
    }
    if (lane < 4) out[n * 4 + lane] = o;
    __builtin_amdgcn_wave_barrier();
  }
}

extern "C" void kernel_launch(void* const* d_in, const int* in_sizes, int n_in,
                              void* d_out, int out_size, void* d_ws, size_t ws_size,
                              hipStream_t stream)
{
  const float* nodes = (const float*)d_in[0];
  const int*   edges = (const int*)d_in[1];
  const float* eatt  = (const float*)d_in[2];
  const float* W_emb = (const float*)d_in[3];
  const float* b_emb = (const float*)d_in[4];
  const float* Wg1   = (const float*)d_in[5];
  const float* bg1   = (const float*)d_in[6];
  const float* Wg2   = (const float*)d_in[7];
  const float* bg2   = (const float*)d_in[8];
  const float* eW1   = (const float*)d_in[9];
  const float* eb1   = (const float*)d_in[10];
  const float* eW2   = (const float*)d_in[11];
  const float* eb2   = (const float*)d_in[12];
  const float* nW1   = (const float*)d_in[13];
  const float* nb1   = (const float*)d_in[14];
  const float* nW2   = (const float*)d_in[15];
  const float* nb2   = (const float*)d_in[16];
  const float* deW1  = (const float*)d_in[17];
  const float* deb1  = (const float*)d_in[18];
  const float* deW2  = (const float*)d_in[19];
  const float* deb2  = (const float*)d_in[20];
  const float* dnW1  = (const float*)d_in[21];
  const float* dnb1  = (const float*)d_in[22];
  const float* dnW2  = (const float*)d_in[23];
  const float* dnb2  = (const float*)d_in[24];
  float* out = (float*)d_out;

  // workspace: h,u,v,agg (4 x 6.4MB) + counts + cursor + bsum/boffs +
  // srow/scol/sea (3 x 1.6MB)  ~= 30.6 MB total
  float* h   = (float*)d_ws;
  float* u   = h + N_NODES * 64;
  float* v   = u + N_NODES * 64;
  float* agg = v + N_NODES * 64;
  int* counts = (int*)(agg + N_NODES * 64);
  int* cursor = counts + N_NODES;
  int* bsum   = cursor + N_NODES;
  int* boffs  = bsum + 128;
  int* srow   = boffs + 128;
  int* scol   = srow + N_EDGES;
  float* sea  = (float*)(scol + N_EDGES);

  const int* rows = edges;
  const int* cols = edges + N_EDGES;

  // --- one-time edge sort by destination row (graph static across layers) ---
  hipMemsetAsync(counts, 0, N_NODES * sizeof(int), stream);
  k_hist<<<400, 256, 0, stream>>>(rows, counts);
  k_scanA<<<NB_SCAN, 256, 0, stream>>>(counts, bsum);
  k_scanB<<<1, 128, 0, stream>>>(bsum, boffs);
  k_scanC<<<NB_SCAN, 256, 0, stream>>>(counts, boffs, cursor);
  k_scatter<<<400, 256, 0, stream>>>(rows, cols, eatt, cursor, srow, scol, sea);

  k_embed<<<(N_NODES + 31) / 32, 256, 0, stream>>>(nodes, W_emb, b_emb, Wg1, bg1, Wg2, bg2, h);

  for (int i = 0; i < 5; ++i) {
    const float* W1i = eW1 + i * 129 * 64;
    k_node_pre<<<1024, 256, 0, stream>>>(h, W1i, u, v, agg);
    k_edge<<<1250, 256, 0, stream>>>(u, v, srow, scol, sea, W1i + 128 * 64,
                                     eb1 + i * 64, eW2 + i * 64 * 64, eb2 + i * 64, agg);
    k_node_post<<<1024, 256, 0, stream>>>(h, agg, nW1 + i * 128 * 64, nb1 + i * 64,
                                          nW2 + i * 64 * 64, nb2 + i * 64);
  }
  // decoder GCL
  k_node_pre<<<1024, 256, 0, stream>>>(h, deW1, u, v, agg);
  k_edge<<<1250, 256, 0, stream>>>(u, v, srow, scol, sea, deW1 + 128 * 64,
                                   deb1, deW2, deb2, agg);
  k_node_final<<<1024, 256, 0, stream>>>(h, agg, dnW1, dnb1, dnW2, dnb2, out);
}

// Round 3
// 725.580 us; speedup vs baseline: 1.6294x; 1.0796x over previous
//
#include <hip/hip_runtime.h>
#include <hip/hip_bf16.h>

#define N_NODES 25000
#define N_EDGES 400000
#define NB_SCAN ((N_NODES + 255) / 256)   // 98
#define EDGE_TILES (N_EDGES / 16)          // 25000
#define TPW 3                              // tiles per wave
#define EDGE_WAVES ((EDGE_TILES + TPW - 1) / TPW)          // 8334
#define EDGE_BLOCKS ((EDGE_WAVES + 3) / 4)                 // 2084

typedef __attribute__((ext_vector_type(8))) short short8;
typedef __attribute__((ext_vector_type(4))) float f32x4;

// fast silu: v_rcp_f32 (<=1 ulp) instead of full-precision divide sequence
__device__ __forceinline__ float silu_f(float x) {
  return x * __builtin_amdgcn_rcpf(1.0f + __expf(-x));
}

__device__ __forceinline__ short f2bf_s(float x) {
  __hip_bfloat16 h = __float2bfloat16(x);
  return *reinterpret_cast<short*>(&h);
}
__device__ __forceinline__ float bf_s2f(short s) {
  __hip_bfloat16 h = *reinterpret_cast<__hip_bfloat16*>(&s);
  return __bfloat162float(h);
}

// ---------------------------------------------------------------------------
// Edge preprocessing: counting sort by destination row (once per launch).
// ---------------------------------------------------------------------------
__global__ __launch_bounds__(256) void k_hist(const int* __restrict__ rows,
                                              int* __restrict__ counts)
{
  int stride = gridDim.x * blockDim.x;
  for (int e = blockIdx.x * blockDim.x + threadIdx.x; e < N_EDGES; e += stride)
    atomicAdd(&counts[rows[e]], 1);
}

__global__ __launch_bounds__(256) void k_scanA(const int* __restrict__ counts,
                                               int* __restrict__ bsum)
{
  __shared__ int sd[256];
  int t = threadIdx.x;
  int i = blockIdx.x * 256 + t;
  int x = (i < N_NODES) ? counts[i] : 0;
  sd[t] = x; __syncthreads();
  for (int d = 128; d > 0; d >>= 1) { if (t < d) sd[t] += sd[t + d]; __syncthreads(); }
  if (t == 0) bsum[blockIdx.x] = sd[0];
}

__global__ __launch_bounds__(128) void k_scanB(const int* __restrict__ bsum,
                                               int* __restrict__ boffs)
{
  __shared__ int buf[128];
  int t = threadIdx.x;
  int x = (t < NB_SCAN) ? bsum[t] : 0;
  buf[t] = x; __syncthreads();
  for (int d = 1; d < 128; d <<= 1) {
    int y = (t >= d) ? buf[t - d] : 0;
    __syncthreads();
    buf[t] += y;
    __syncthreads();
  }
  if (t < NB_SCAN) boffs[t] = buf[t] - x;   // exclusive block offsets
}

__global__ __launch_bounds__(256) void k_scanC(const int* __restrict__ counts,
                                               const int* __restrict__ boffs,
                                               int* __restrict__ cursor)
{
  __shared__ int buf[256];
  int t = threadIdx.x;
  int i = blockIdx.x * 256 + t;
  int x = (i < N_NODES) ? counts[i] : 0;
  buf[t] = x; __syncthreads();
  for (int d = 1; d < 256; d <<= 1) {
    int y = (t >= d) ? buf[t - d] : 0;
    __syncthreads();
    buf[t] += y;
    __syncthreads();
  }
  if (i < N_NODES) cursor[i] = boffs[blockIdx.x] + buf[t] - x;
}

__global__ __launch_bounds__(256) void k_scatter(
    const int* __restrict__ rows, const int* __restrict__ cols,
    const float* __restrict__ eatt, int* __restrict__ cursor,
    int* __restrict__ srow, int* __restrict__ scol, float* __restrict__ sea)
{
  int stride = gridDim.x * blockDim.x;
  for (int e = blockIdx.x * blockDim.x + threadIdx.x; e < N_EDGES; e += stride) {
    int r = rows[e];
    int pos = atomicAdd(&cursor[r], 1);
    srow[pos] = r;
    scol[pos] = cols[e];
    sea[pos] = eatt[e];
  }
}

// ---------------------------------------------------------------------------
// Embedding: h = silu([h_g0|h_g1] @ Wg1 + bg1) @ Wg2 + bg2
// ---------------------------------------------------------------------------
__global__ __launch_bounds__(256) void k_embed(
    const float* __restrict__ nodes, const float* __restrict__ W_emb, const float* __restrict__ b_emb,
    const float* __restrict__ Wg1, const float* __restrict__ bg1,
    const float* __restrict__ Wg2, const float* __restrict__ bg2,
    float* __restrict__ h)
{
  __shared__ float We[5 * 64];
  __shared__ float W1[128 * 64];
  __shared__ float W2[64 * 64];
  __shared__ float be[64], b1s[64], b2s[64];
  __shared__ __align__(16) float hbuf[4][128];
  __shared__ __align__(16) float tbuf[4][64];

  for (int t = threadIdx.x; t < 128 * 64; t += 256) W1[t] = Wg1[t];
  for (int t = threadIdx.x; t < 64 * 64; t += 256) W2[t] = Wg2[t];
  for (int t = threadIdx.x; t < 5 * 64; t += 256) We[t] = W_emb[t];
  if (threadIdx.x < 64) {
    be[threadIdx.x]  = b_emb[threadIdx.x];
    b1s[threadIdx.x] = bg1[threadIdx.x];
    b2s[threadIdx.x] = bg2[threadIdx.x];
  }
  __syncthreads();

  const int lane = threadIdx.x & 63;
  const int wv = threadIdx.x >> 6;
  float* hb = hbuf[wv];
  float* tb = tbuf[wv];
  const float4* hb4 = (const float4*)hb;
  const float4* tb4 = (const float4*)tb;

  int n0 = blockIdx.x * 32 + wv * 8;
  int n1 = min(n0 + 8, N_NODES);
  for (int n = n0; n < n1; ++n) {
    float x0 = nodes[n * 5 + 0], x1 = nodes[n * 5 + 1],
          x2 = nodes[n * 5 + 2], x3 = nodes[n * 5 + 3],
          x4 = nodes[n * 5 + 4];
    float w0 = We[0 * 64 + lane], w1 = We[1 * 64 + lane], w2 = We[2 * 64 + lane],
          w3 = We[3 * 64 + lane], w4 = We[4 * 64 + lane];
    float base = be[lane] + x4 * w4;
    float s = x0 * w0 + x1 * w1 + x2 * w2 + x3 * w3;
    hb[lane] = base + s;
    hb[64 + lane] = base - s;
    __builtin_amdgcn_wave_barrier();

    float t = b1s[lane];
#pragma unroll
    for (int k4 = 0; k4 < 32; ++k4) {
      float4 hh = hb4[k4];
      t += hh.x * W1[(4 * k4 + 0) * 64 + lane];
      t += hh.y * W1[(4 * k4 + 1) * 64 + lane];
      t += hh.z * W1[(4 * k4 + 2) * 64 + lane];
      t += hh.w * W1[(4 * k4 + 3) * 64 + lane];
    }
    t = silu_f(t);
    __builtin_amdgcn_wave_barrier();
    tb[lane] = t;
    __builtin_amdgcn_wave_barrier();

    float o = b2s[lane];
#pragma unroll
    for (int k4 = 0; k4 < 16; ++k4) {
      float4 tt = tb4[k4];
      o += tt.x * W2[(4 * k4 + 0) * 64 + lane];
      o += tt.y * W2[(4 * k4 + 1) * 64 + lane];
      o += tt.z * W2[(4 * k4 + 2) * 64 + lane];
      o += tt.w * W2[(4 * k4 + 3) * 64 + lane];
    }
    h[n * 64 + lane] = o;
    __builtin_amdgcn_wave_barrier();
  }
}

// ---------------------------------------------------------------------------
// Per-layer node precompute: u = h @ eW1[0:64], v = h @ eW1[64:128].
// Zero-inits agg. Software-prefetches next node's h row.
// ---------------------------------------------------------------------------
__global__ __launch_bounds__(256) void k_node_pre(
    const float* __restrict__ h, const float* __restrict__ eW1,
    float* __restrict__ u, float* __restrict__ v, float* __restrict__ agg)
{
  const int lane = threadIdx.x & 63;
  const int wv = threadIdx.x >> 6;
  float ar[64], br[64];
#pragma unroll
  for (int k = 0; k < 64; ++k) {
    ar[k] = eW1[k * 64 + lane];
    br[k] = eW1[(64 + k) * 64 + lane];
  }
  __shared__ __align__(16) float hbuf[4][64];
  float* hb = hbuf[wv];
  const float4* hb4 = (const float4*)hb;

  int nw = gridDim.x * 4;
  int wid = blockIdx.x * 4 + wv;
  int per = (N_NODES + nw - 1) / nw;
  int n0 = wid * per, n1 = min(N_NODES, n0 + per);
  if (n0 >= n1) return;

  float hv = h[n0 * 64 + lane];
  for (int n = n0; n < n1; ++n) {
    float hnext = (n + 1 < n1) ? h[(n + 1) * 64 + lane] : 0.f;  // prefetch
    hb[lane] = hv;
    agg[n * 64 + lane] = 0.f;
    __builtin_amdgcn_wave_barrier();
    float uu = 0.f, vv = 0.f;
#pragma unroll
    for (int k4 = 0; k4 < 16; ++k4) {
      float4 hh = hb4[k4];
      uu += hh.x * ar[4 * k4 + 0]; vv += hh.x * br[4 * k4 + 0];
      uu += hh.y * ar[4 * k4 + 1]; vv += hh.y * br[4 * k4 + 1];
      uu += hh.z * ar[4 * k4 + 2]; vv += hh.z * br[4 * k4 + 2];
      uu += hh.w * ar[4 * k4 + 3]; vv += hh.w * br[4 * k4 + 3];
    }
    u[n * 64 + lane] = uu;
    v[n * 64 + lane] = vv;
    __builtin_amdgcn_wave_barrier();
    hv = hnext;
  }
}

// ---------------------------------------------------------------------------
// Fused edge kernel over SORTED edges, dense 16-edge tiles, TPW tiles per
// wave, running segmented reduction epilogue (see round-2 comments).
// New: row/col/ea hoisted to SGPRs via readlane -> scalar addressing (SALU)
// for the u/v gathers; fast-rcp silu.
// ---------------------------------------------------------------------------
__global__ __launch_bounds__(256) void k_edge(
    const float* __restrict__ u, const float* __restrict__ v,
    const int* __restrict__ srow, const int* __restrict__ scol,
    const float* __restrict__ sea,
    const float* __restrict__ wea, const float* __restrict__ eb1,
    const float* __restrict__ W2, const float* __restrict__ eb2,
    float* __restrict__ agg)
{
  const int lane = threadIdx.x & 63;
  const int wv = threadIdx.x >> 6;
  const int n16 = lane & 15;
  const int quad = lane >> 4;

  // B fragments (W2 columns), split hi/lo, resident in VGPRs.
  short8 Whi[2][4], Wlo[2][4];
#pragma unroll
  for (int s = 0; s < 2; ++s) {
#pragma unroll
    for (int nt = 0; nt < 4; ++nt) {
#pragma unroll
      for (int j = 0; j < 8; ++j) {
        float w2v = W2[(s * 32 + quad * 8 + j) * 64 + nt * 16 + n16];
        short hi = f2bf_s(w2v);
        Whi[s][nt][j] = hi;
        Wlo[s][nt][j] = f2bf_s(w2v - bf_s2f(hi));
      }
    }
  }
  float we = wea[lane];
  float b1v = eb1[lane];
  float b2v[4];
#pragma unroll
  for (int nt = 0; nt < 4; ++nt) b2v[nt] = eb2[nt * 16 + n16];

  __shared__ float Tl[4][64 * 17];   // [feat][edge], pad 17: <=2-way conflicts
  float* T = Tl[wv];

  const int wid = blockIdx.x * 4 + wv;
  const int tile0 = wid * TPW;
  const int tile1 = min(tile0 + TPW, EDGE_TILES);

  int cur_row = -1;
  bool first_atomic = true;
  float asum[4] = {0.f, 0.f, 0.f, 0.f};

  auto reduce_pick = [&](float a0, float a1, float a2, float a3) -> float {
    a0 += __shfl_xor(a0, 16); a0 += __shfl_xor(a0, 32);
    a1 += __shfl_xor(a1, 16); a1 += __shfl_xor(a1, 32);
    a2 += __shfl_xor(a2, 16); a2 += __shfl_xor(a2, 32);
    a3 += __shfl_xor(a3, 16); a3 += __shfl_xor(a3, 32);
    float o = a0;
    o = (quad == 1) ? a1 : o;
    o = (quad == 2) ? a2 : o;
    o = (quad == 3) ? a3 : o;
    return o;
  };

  for (int tile = tile0; tile < tile1; ++tile) {
    int e0 = tile * 16;
    int r16a = srow[e0 + n16];
    int c16a = scol[e0 + n16];
    float ea16 = sea[e0 + n16];

    // phase 1: 16 edges, lane = feature. Row/col/ea are wave-uniform per
    // edge slot -> readlane to SGPR so address gen is SALU + saddr loads.
#pragma unroll
    for (int e = 0; e < 16; ++e) {
      int r = __builtin_amdgcn_readlane(r16a, e);
      int c = __builtin_amdgcn_readlane(c16a, e);
      float ea = __int_as_float(__builtin_amdgcn_readlane(__float_as_int(ea16), e));
      float tt = u[r * 64 + lane] + v[c * 64 + lane] + ea * we + b1v;
      T[lane * 17 + e] = silu_f(tt);
    }
    __builtin_amdgcn_wave_barrier();

    f32x4 acc[4] = {};
#pragma unroll
    for (int s = 0; s < 2; ++s) {
      short8 ahi, alo;
#pragma unroll
      for (int j = 0; j < 8; ++j) {
        float tv = T[(s * 32 + quad * 8 + j) * 17 + n16];
        short hi = f2bf_s(tv);
        ahi[j] = hi;
        alo[j] = f2bf_s(tv - bf_s2f(hi));
      }
#pragma unroll
      for (int nt = 0; nt < 4; ++nt) {
        acc[nt] = __builtin_amdgcn_mfma_f32_16x16x32_bf16(ahi, Whi[s][nt], acc[nt], 0, 0, 0);
        acc[nt] = __builtin_amdgcn_mfma_f32_16x16x32_bf16(ahi, Wlo[s][nt], acc[nt], 0, 0, 0);
        acc[nt] = __builtin_amdgcn_mfma_f32_16x16x32_bf16(alo, Whi[s][nt], acc[nt], 0, 0, 0);
      }
    }
    __builtin_amdgcn_wave_barrier();

    // epilogue: silu, then running segmented reduce by row.
    float ev[4][4];   // [reg][nt], compile-time indices (stays in VGPRs)
#pragma unroll
    for (int reg = 0; reg < 4; ++reg)
#pragma unroll
      for (int nt = 0; nt < 4; ++nt)
        ev[reg][nt] = silu_f(acc[nt][reg] + b2v[nt]);

    // wave-uniform row-boundary mask over the 16 slots
    int rup = __shfl_up(r16a, 1);
    bool nf = (lane < 16) && ((lane == 0) ? (r16a != cur_row) : (r16a != rup));
    unsigned mask = (unsigned)(__ballot(nf) & 0xFFFFull);

    int s = 0;
    while (s < 16) {
      if ((mask >> s) & 1u) {
        if (cur_row >= 0) {
          float o = reduce_pick(asum[0], asum[1], asum[2], asum[3]);
          if (first_atomic) { unsafeAtomicAdd(&agg[cur_row * 64 + lane], o); first_atomic = false; }
          else agg[cur_row * 64 + lane] = o;
        }
        asum[0] = asum[1] = asum[2] = asum[3] = 0.f;
        cur_row = __shfl(r16a, s);
      }
      unsigned rem = mask & ~((2u << s) - 1u);   // boundaries strictly after s
      int e = rem ? (__ffs(rem) - 1) : 16;
#pragma unroll
      for (int reg = 0; reg < 4; ++reg) {
        int m = quad * 4 + reg;
        bool in = (m >= s) && (m < e);
        asum[0] += in ? ev[reg][0] : 0.f;
        asum[1] += in ? ev[reg][1] : 0.f;
        asum[2] += in ? ev[reg][2] : 0.f;
        asum[3] += in ? ev[reg][3] : 0.f;
      }
      s = e;
    }
    __builtin_amdgcn_wave_barrier();
  }

  // final flush: row may continue into the next wave's range -> atomic
  if (cur_row >= 0) {
    float o = reduce_pick(asum[0], asum[1], asum[2], asum[3]);
    unsafeAtomicAdd(&agg[cur_row * 64 + lane], o);
  }
}

// ---------------------------------------------------------------------------
// Per-layer node MLP: h = silu(h@nW1[0:64] + agg@nW1[64:128] + nb1) @ nW2 + nb2
// Software-prefetches next node's h/agg rows.
// ---------------------------------------------------------------------------
__global__ __launch_bounds__(256, 2) void k_node_post(
    float* __restrict__ h, const float* __restrict__ agg,
    const float* __restrict__ nW1, const float* __restrict__ nb1,
    const float* __restrict__ nW2, const float* __restrict__ nb2)
{
  const int lane = threadIdx.x & 63;
  const int wv = threadIdx.x >> 6;
  float ar[64], br[64], wr[64];
#pragma unroll
  for (int k = 0; k < 64; ++k) {
    ar[k] = nW1[k * 64 + lane];
    br[k] = nW1[(64 + k) * 64 + lane];
    wr[k] = nW2[k * 64 + lane];
  }
  float b1v = nb1[lane], b2v = nb2[lane];
  __shared__ __align__(16) float hbuf[4][64];
  __shared__ __align__(16) float abuf[4][64];
  __shared__ __align__(16) float tbuf[4][64];
  float* hb = hbuf[wv]; float* ab = abuf[wv]; float* tb = tbuf[wv];
  const float4* hb4 = (const float4*)hb;
  const float4* ab4 = (const float4*)ab;
  const float4* tb4 = (const float4*)tb;

  int nw = gridDim.x * 4;
  int wid = blockIdx.x * 4 + wv;
  int per = (N_NODES + nw - 1) / nw;
  int n0 = wid * per, n1 = min(N_NODES, n0 + per);
  if (n0 >= n1) return;

  float hv = h[n0 * 64 + lane];
  float av = agg[n0 * 64 + lane];
  for (int n = n0; n < n1; ++n) {
    float hnext = 0.f, anext = 0.f;
    if (n + 1 < n1) {                      // prefetch next row
      hnext = h[(n + 1) * 64 + lane];
      anext = agg[(n + 1) * 64 + lane];
    }
    hb[lane] = hv;
    ab[lane] = av;
    __builtin_amdgcn_wave_barrier();
    float t = b1v;
#pragma unroll
    for (int k4 = 0; k4 < 16; ++k4) {
      float4 hh = hb4[k4];
      float4 aa = ab4[k4];
      t += hh.x * ar[4 * k4 + 0] + aa.x * br[4 * k4 + 0];
      t += hh.y * ar[4 * k4 + 1] + aa.y * br[4 * k4 + 1];
      t += hh.z * ar[4 * k4 + 2] + aa.z * br[4 * k4 + 2];
      t += hh.w * ar[4 * k4 + 3] + aa.w * br[4 * k4 + 3];
    }
    t = silu_f(t);
    __builtin_amdgcn_wave_barrier();
    tb[lane] = t;
    __builtin_amdgcn_wave_barrier();
    float o = b2v;
#pragma unroll
    for (int k4 = 0; k4 < 16; ++k4) {
      float4 tt = tb4[k4];
      o += tt.x * wr[4 * k4 + 0];
      o += tt.y * wr[4 * k4 + 1];
      o += tt.z * wr[4 * k4 + 2];
      o += tt.w * wr[4 * k4 + 3];
    }
    h[n * 64 + lane] = o;
    __builtin_amdgcn_wave_barrier();
    hv = hnext; av = anext;
  }
}

// ---------------------------------------------------------------------------
// Final node MLP: out = silu(concat(h,agg) @ dnW1 + dnb1) @ dnW2 + dnb2, (N,4)
// ---------------------------------------------------------------------------
__global__ __launch_bounds__(256, 2) void k_node_final(
    const float* __restrict__ h, const float* __restrict__ agg,
    const float* __restrict__ dnW1, const float* __restrict__ dnb1,
    const float* __restrict__ dnW2, const float* __restrict__ dnb2,
    float* __restrict__ out)
{
  const int lane = threadIdx.x & 63;
  const int wv = threadIdx.x >> 6;
  float ar[64], br[64], wr[64];
#pragma unroll
  for (int k = 0; k < 64; ++k) {
    ar[k] = dnW1[k * 64 + lane];
    br[k] = dnW1[(64 + k) * 64 + lane];
    wr[k] = dnW2[k * 4 + (lane & 3)];
  }
  float b1v = dnb1[lane];
  float b2v = dnb2[lane & 3];
  __shared__ __align__(16) float hbuf[4][64];
  __shared__ __align__(16) float abuf[4][64];
  __shared__ __align__(16) float tbuf[4][64];
  float* hb = hbuf[wv]; float* ab = abuf[wv]; float* tb = tbuf[wv];
  const float4* hb4 = (const float4*)hb;
  const float4* ab4 = (const float4*)ab;
  const float4* tb4 = (const float4*)tb;

  int nw = gridDim.x * 4;
  int wid = blockIdx.x * 4 + wv;
  int per = (N_NODES + nw - 1) / nw;
  int n0 = wid * per, n1 = min(N_NODES, n0 + per);
  if (n0 >= n1) return;

  float hv = h[n0 * 64 + lane];
  float av = agg[n0 * 64 + lane];
  for (int n = n0; n < n1; ++n) {
    float hnext = 0.f, anext = 0.f;
    if (n + 1 < n1) {
      hnext = h[(n + 1) * 64 + lane];
      anext = agg[(n + 1) * 64 + lane];
    }
    hb[lane] = hv;
    ab[lane] = av;
    __builtin_amdgcn_wave_barrier();
    float t = b1v;
#pragma unroll
    for (int k4 = 0; k4 < 16; ++k4) {
      float4 hh = hb4[k4];
      float4 aa = ab4[k4];
      t += hh.x * ar[4 * k4 + 0] + aa.x * br[4 * k4 + 0];
      t += hh.y * ar[4 * k4 + 1] + aa.y * br[4 * k4 + 1];
      t += hh.z * ar[4 * k4 + 2] + aa.z * br[4 * k4 + 2];
      t += hh.w * ar[4 * k4 + 3] + aa.w * br[4 * k4 + 3];
    }
    t = silu_f(t);
    __builtin_amdgcn_wave_barrier();
    tb[lane] = t;
    __builtin_amdgcn_wave_barrier();
    float o = b2v;
#pragma unroll
    for (int k4 = 0; k4 < 16; ++k4) {
      float4 tt = tb4[k4];
      o += tt.x * wr[4 * k4 + 0];
      o += tt.y * wr[4 * k4 + 1];
      o += tt.z * wr[4 * k4 + 2];
      o += tt.w * wr[4 * k4 + 3];
    }
    if (lane < 4) out[n * 4 + lane] = o;
    __builtin_amdgcn_wave_barrier();
    hv = hnext; av = anext;
  }
}

extern "C" void kernel_launch(void* const* d_in, const int* in_sizes, int n_in,
                              void* d_out, int out_size, void* d_ws, size_t ws_size,
                              hipStream_t stream)
{
  const float* nodes = (const float*)d_in[0];
  const int*   edges = (const int*)d_in[1];
  const float* eatt  = (const float*)d_in[2];
  const float* W_emb = (const float*)d_in[3];
  const float* b_emb = (const float*)d_in[4];
  const float* Wg1   = (const float*)d_in[5];
  const float* bg1   = (const float*)d_in[6];
  const float* Wg2   = (const float*)d_in[7];
  const float* bg2   = (const float*)d_in[8];
  const float* eW1   = (const float*)d_in[9];
  const float* eb1   = (const float*)d_in[10];
  const float* eW2   = (const float*)d_in[11];
  const float* eb2   = (const float*)d_in[12];
  const float* nW1   = (const float*)d_in[13];
  const float* nb1   = (const float*)d_in[14];
  const float* nW2   = (const float*)d_in[15];
  const float* nb2   = (const float*)d_in[16];
  const float* deW1  = (const float*)d_in[17];
  const float* deb1  = (const float*)d_in[18];
  const float* deW2  = (const float*)d_in[19];
  const float* deb2  = (const float*)d_in[20];
  const float* dnW1  = (const float*)d_in[21];
  const float* dnb1  = (const float*)d_in[22];
  const float* dnW2  = (const float*)d_in[23];
  const float* dnb2  = (const float*)d_in[24];
  float* out = (float*)d_out;

  float* h   = (float*)d_ws;
  float* u   = h + N_NODES * 64;
  float* v   = u + N_NODES * 64;
  float* agg = v + N_NODES * 64;
  int* counts = (int*)(agg + N_NODES * 64);
  int* cursor = counts + N_NODES;
  int* bsum   = cursor + N_NODES;
  int* boffs  = bsum + 128;
  int* srow   = boffs + 128;
  int* scol   = srow + N_EDGES;
  float* sea  = (float*)(scol + N_EDGES);

  const int* rows = edges;
  const int* cols = edges + N_EDGES;

  // --- one-time edge sort by destination row (graph static across layers) ---
  hipMemsetAsync(counts, 0, N_NODES * sizeof(int), stream);
  k_hist<<<400, 256, 0, stream>>>(rows, counts);
  k_scanA<<<NB_SCAN, 256, 0, stream>>>(counts, bsum);
  k_scanB<<<1, 128, 0, stream>>>(bsum, boffs);
  k_scanC<<<NB_SCAN, 256, 0, stream>>>(counts, boffs, cursor);
  k_scatter<<<400, 256, 0, stream>>>(rows, cols, eatt, cursor, srow, scol, sea);

  k_embed<<<(N_NODES + 31) / 32, 256, 0, stream>>>(nodes, W_emb, b_emb, Wg1, bg1, Wg2, bg2, h);

  for (int i = 0; i < 5; ++i) {
    const float* W1i = eW1 + i * 129 * 64;
    k_node_pre<<<1024, 256, 0, stream>>>(h, W1i, u, v, agg);
    k_edge<<<EDGE_BLOCKS, 256, 0, stream>>>(u, v, srow, scol, sea, W1i + 128 * 64,
                                            eb1 + i * 64, eW2 + i * 64 * 64, eb2 + i * 64, agg);
    k_node_post<<<1024, 256, 0, stream>>>(h, agg, nW1 + i * 128 * 64, nb1 + i * 64,
                                          nW2 + i * 64 * 64, nb2 + i * 64);
  }
  // decoder GCL
  k_node_pre<<<1024, 256, 0, stream>>>(h, deW1, u, v, agg);
  k_edge<<<EDGE_BLOCKS, 256, 0, stream>>>(u, v, srow, scol, sea, deW1 + 128 * 64,
                                          deb1, deW2, deb2, agg);
  k_node_final<<<1024, 256, 0, stream>>>(h, agg, dnW1, dnb1, dnW2, dnb2, out);
}

// Round 4
// 619.618 us; speedup vs baseline: 1.9081x; 1.1710x over previous
//
#include <hip/hip_runtime.h>
#include <hip/hip_bf16.h>

#define N_NODES 25000
#define N_EDGES 400000
#define NB_SCAN ((N_NODES + 255) / 256)   // 98
#define EDGE_TILES (N_EDGES / 16)          // 25000
#define TPW 3                              // tiles per wave (edge kernel)
#define EDGE_WAVES ((EDGE_TILES + TPW - 1) / TPW)          // 8334
#define EDGE_BLOCKS ((EDGE_WAVES + 3) / 4)                 // 2084
#define NODE_TILES ((N_NODES + 15) / 16)   // 1563
#define NODE_BLOCKS 521                    // 1563 = 3 * 521 exactly

typedef __attribute__((ext_vector_type(8))) short short8;
typedef __attribute__((ext_vector_type(4))) float f32x4;

// fast silu: v_rcp_f32 (<=1 ulp) instead of full-precision divide sequence
__device__ __forceinline__ float silu_f(float x) {
  return x * __builtin_amdgcn_rcpf(1.0f + __expf(-x));
}

__device__ __forceinline__ short f2bf_s(float x) {
  __hip_bfloat16 h = __float2bfloat16(x);
  return *reinterpret_cast<short*>(&h);
}
__device__ __forceinline__ float bf_s2f(short s) {
  __hip_bfloat16 h = *reinterpret_cast<__hip_bfloat16*>(&s);
  return __bfloat162float(h);
}

// --- shared MFMA helpers (layout identical to the verified k_edge path) ----
// A-frag from LDS tile T[k][m] (stride 17): A[m=n16][k=s*32+quad*8+j]
__device__ __forceinline__ void load_afrag(const float* T, int s, int quad, int n16,
                                           short8& ahi, short8& alo) {
#pragma unroll
  for (int j = 0; j < 8; ++j) {
    float tv = T[(s * 32 + quad * 8 + j) * 17 + n16];
    short hi = f2bf_s(tv);
    ahi[j] = hi;
    alo[j] = f2bf_s(tv - bf_s2f(hi));
  }
}
// B-frag from global W[k][n] (row-major, 64 cols): B[k=k0+j][n=col]
__device__ __forceinline__ void load_bfrag(const float* __restrict__ W, int k0, int col,
                                           short8& bhi, short8& blo) {
#pragma unroll
  for (int j = 0; j < 8; ++j) {
    float w = W[(k0 + j) * 64 + col];
    short hi = f2bf_s(w);
    bhi[j] = hi;
    blo[j] = f2bf_s(w - bf_s2f(hi));
  }
}
// split-bf16 3-product ~fp32 MFMA
__device__ __forceinline__ f32x4 mfma3(short8 ahi, short8 alo, short8 bhi, short8 blo,
                                       f32x4 acc) {
  acc = __builtin_amdgcn_mfma_f32_16x16x32_bf16(ahi, bhi, acc, 0, 0, 0);
  acc = __builtin_amdgcn_mfma_f32_16x16x32_bf16(ahi, blo, acc, 0, 0, 0);
  acc = __builtin_amdgcn_mfma_f32_16x16x32_bf16(alo, bhi, acc, 0, 0, 0);
  return acc;
}

// ---------------------------------------------------------------------------
// Edge preprocessing: counting sort by destination row (once per launch).
// ---------------------------------------------------------------------------
__global__ __launch_bounds__(256) void k_hist(const int* __restrict__ rows,
                                              int* __restrict__ counts)
{
  int stride = gridDim.x * blockDim.x;
  for (int e = blockIdx.x * blockDim.x + threadIdx.x; e < N_EDGES; e += stride)
    atomicAdd(&counts[rows[e]], 1);
}

__global__ __launch_bounds__(256) void k_scanA(const int* __restrict__ counts,
                                               int* __restrict__ bsum)
{
  __shared__ int sd[256];
  int t = threadIdx.x;
  int i = blockIdx.x * 256 + t;
  int x = (i < N_NODES) ? counts[i] : 0;
  sd[t] = x; __syncthreads();
  for (int d = 128; d > 0; d >>= 1) { if (t < d) sd[t] += sd[t + d]; __syncthreads(); }
  if (t == 0) bsum[blockIdx.x] = sd[0];
}

__global__ __launch_bounds__(128) void k_scanB(const int* __restrict__ bsum,
                                               int* __restrict__ boffs)
{
  __shared__ int buf[128];
  int t = threadIdx.x;
  int x = (t < NB_SCAN) ? bsum[t] : 0;
  buf[t] = x; __syncthreads();
  for (int d = 1; d < 128; d <<= 1) {
    int y = (t >= d) ? buf[t - d] : 0;
    __syncthreads();
    buf[t] += y;
    __syncthreads();
  }
  if (t < NB_SCAN) boffs[t] = buf[t] - x;   // exclusive block offsets
}

__global__ __launch_bounds__(256) void k_scanC(const int* __restrict__ counts,
                                               const int* __restrict__ boffs,
                                               int* __restrict__ cursor)
{
  __shared__ int buf[256];
  int t = threadIdx.x;
  int i = blockIdx.x * 256 + t;
  int x = (i < N_NODES) ? counts[i] : 0;
  buf[t] = x; __syncthreads();
  for (int d = 1; d < 256; d <<= 1) {
    int y = (t >= d) ? buf[t - d] : 0;
    __syncthreads();
    buf[t] += y;
    __syncthreads();
  }
  if (i < N_NODES) cursor[i] = boffs[blockIdx.x] + buf[t] - x;
}

__global__ __launch_bounds__(256) void k_scatter(
    const int* __restrict__ rows, const int* __restrict__ cols,
    const float* __restrict__ eatt, int* __restrict__ cursor,
    int* __restrict__ srow, int* __restrict__ scol, float* __restrict__ sea)
{
  int stride = gridDim.x * blockDim.x;
  for (int e = blockIdx.x * blockDim.x + threadIdx.x; e < N_EDGES; e += stride) {
    int r = rows[e];
    int pos = atomicAdd(&cursor[r], 1);
    srow[pos] = r;
    scol[pos] = cols[e];
    sea[pos] = eatt[e];
  }
}

// ---------------------------------------------------------------------------
// Embedding: h = silu([h_g0|h_g1] @ Wg1 + bg1) @ Wg2 + bg2
// ---------------------------------------------------------------------------
__global__ __launch_bounds__(256) void k_embed(
    const float* __restrict__ nodes, const float* __restrict__ W_emb, const float* __restrict__ b_emb,
    const float* __restrict__ Wg1, const float* __restrict__ bg1,
    const float* __restrict__ Wg2, const float* __restrict__ bg2,
    float* __restrict__ h)
{
  __shared__ float We[5 * 64];
  __shared__ float W1[128 * 64];
  __shared__ float W2[64 * 64];
  __shared__ float be[64], b1s[64], b2s[64];
  __shared__ __align__(16) float hbuf[4][128];
  __shared__ __align__(16) float tbuf[4][64];

  for (int t = threadIdx.x; t < 128 * 64; t += 256) W1[t] = Wg1[t];
  for (int t = threadIdx.x; t < 64 * 64; t += 256) W2[t] = Wg2[t];
  for (int t = threadIdx.x; t < 5 * 64; t += 256) We[t] = W_emb[t];
  if (threadIdx.x < 64) {
    be[threadIdx.x]  = b_emb[threadIdx.x];
    b1s[threadIdx.x] = bg1[threadIdx.x];
    b2s[threadIdx.x] = bg2[threadIdx.x];
  }
  __syncthreads();

  const int lane = threadIdx.x & 63;
  const int wv = threadIdx.x >> 6;
  float* hb = hbuf[wv];
  float* tb = tbuf[wv];
  const float4* hb4 = (const float4*)hb;
  const float4* tb4 = (const float4*)tb;

  int n0 = blockIdx.x * 32 + wv * 8;
  int n1 = min(n0 + 8, N_NODES);
  for (int n = n0; n < n1; ++n) {
    float x0 = nodes[n * 5 + 0], x1 = nodes[n * 5 + 1],
          x2 = nodes[n * 5 + 2], x3 = nodes[n * 5 + 3],
          x4 = nodes[n * 5 + 4];
    float w0 = We[0 * 64 + lane], w1 = We[1 * 64 + lane], w2 = We[2 * 64 + lane],
          w3 = We[3 * 64 + lane], w4 = We[4 * 64 + lane];
    float base = be[lane] + x4 * w4;
    float s = x0 * w0 + x1 * w1 + x2 * w2 + x3 * w3;
    hb[lane] = base + s;
    hb[64 + lane] = base - s;
    __builtin_amdgcn_wave_barrier();

    float t = b1s[lane];
#pragma unroll
    for (int k4 = 0; k4 < 32; ++k4) {
      float4 hh = hb4[k4];
      t += hh.x * W1[(4 * k4 + 0) * 64 + lane];
      t += hh.y * W1[(4 * k4 + 1) * 64 + lane];
      t += hh.z * W1[(4 * k4 + 2) * 64 + lane];
      t += hh.w * W1[(4 * k4 + 3) * 64 + lane];
    }
    t = silu_f(t);
    __builtin_amdgcn_wave_barrier();
    tb[lane] = t;
    __builtin_amdgcn_wave_barrier();

    float o = b2s[lane];
#pragma unroll
    for (int k4 = 0; k4 < 16; ++k4) {
      float4 tt = tb4[k4];
      o += tt.x * W2[(4 * k4 + 0) * 64 + lane];
      o += tt.y * W2[(4 * k4 + 1) * 64 + lane];
      o += tt.z * W2[(4 * k4 + 2) * 64 + lane];
      o += tt.w * W2[(4 * k4 + 3) * 64 + lane];
    }
    h[n * 64 + lane] = o;
    __builtin_amdgcn_wave_barrier();
  }
}

// ---------------------------------------------------------------------------
// MFMA node precompute (used once after embed): u = h@eW1[0:64],
// v = h@eW1[64:128]; zero-inits agg. 16-node tiles, 4 waves/block, wave wv
// owns output columns [wv*16, wv*16+16).
// ---------------------------------------------------------------------------
__global__ __launch_bounds__(256, 2) void k_pre_mfma(
    const float* __restrict__ h, const float* __restrict__ eW1,
    float* __restrict__ u, float* __restrict__ v, float* __restrict__ agg)
{
  const int lane = threadIdx.x & 63;
  const int wv = threadIdx.x >> 6;
  const int n16 = lane & 15;
  const int quad = lane >> 4;
  const int col = wv * 16 + n16;

  short8 Uhi[2], Ulo[2], Vhi[2], Vlo[2];
#pragma unroll
  for (int s = 0; s < 2; ++s) {
    load_bfrag(eW1, s * 32 + quad * 8, col, Uhi[s], Ulo[s]);
    load_bfrag(eW1 + 64 * 64, s * 32 + quad * 8, col, Vhi[s], Vlo[s]);
  }

  __shared__ float Ta[64 * 17];
  __shared__ float Tu[64 * 17];
  __shared__ float Tv[64 * 17];

  for (int tile = blockIdx.x; tile < NODE_TILES; tile += gridDim.x) {
    int n0 = tile * 16;
#pragma unroll
    for (int e4 = 0; e4 < 4; ++e4) {
      int e = wv * 4 + e4;
      int n = min(n0 + e, N_NODES - 1);
      Ta[lane * 17 + e] = h[n * 64 + lane];
    }
    __syncthreads();
    f32x4 aU = {}, aV = {};
#pragma unroll
    for (int s = 0; s < 2; ++s) {
      short8 ahi, alo;
      load_afrag(Ta, s, quad, n16, ahi, alo);
      aU = mfma3(ahi, alo, Uhi[s], Ulo[s], aU);
      aV = mfma3(ahi, alo, Vhi[s], Vlo[s], aV);
    }
#pragma unroll
    for (int r = 0; r < 4; ++r) {
      Tu[col * 17 + quad * 4 + r] = aU[r];
      Tv[col * 17 + quad * 4 + r] = aV[r];
    }
    __syncthreads();
#pragma unroll
    for (int e4 = 0; e4 < 4; ++e4) {
      int e = wv * 4 + e4;
      int n = n0 + e;
      if (n < N_NODES) {
        u[n * 64 + lane] = Tu[lane * 17 + e];
        v[n * 64 + lane] = Tv[lane * 17 + e];
        agg[n * 64 + lane] = 0.f;
      }
    }
    __syncthreads();
  }
}

// ---------------------------------------------------------------------------
// Fused MFMA node kernel (layer i post + layer i+1 pre):
//   t   = silu([h|agg] @ nW1 + nb1)          (K=128)
//   h'  = t @ nW2 + nb2                       (K=64)
//   u   = h' @ eW1n[0:64], v = h' @ eW1n[64:128]; agg <- 0
// 16-node tiles, 4 waves/block, wave wv owns output cols [wv*16, wv*16+16).
// All GEMMs via the verified split-bf16 3-product MFMA recipe.
// ---------------------------------------------------------------------------
__global__ __launch_bounds__(256, 2) void k_postfused(
    float* __restrict__ h, float* __restrict__ agg,
    const float* __restrict__ nW1, const float* __restrict__ nb1,
    const float* __restrict__ nW2, const float* __restrict__ nb2,
    const float* __restrict__ eW1n,
    float* __restrict__ u, float* __restrict__ v)
{
  const int lane = threadIdx.x & 63;
  const int wv = threadIdx.x >> 6;
  const int n16 = lane & 15;
  const int quad = lane >> 4;
  const int col = wv * 16 + n16;

  short8 W1hi[4], W1lo[4], W2hi[2], W2lo[2], Uhi[2], Ulo[2], Vhi[2], Vlo[2];
#pragma unroll
  for (int s = 0; s < 4; ++s)
    load_bfrag(nW1, s * 32 + quad * 8, col, W1hi[s], W1lo[s]);
#pragma unroll
  for (int s = 0; s < 2; ++s) {
    load_bfrag(nW2, s * 32 + quad * 8, col, W2hi[s], W2lo[s]);
    load_bfrag(eW1n, s * 32 + quad * 8, col, Uhi[s], Ulo[s]);
    load_bfrag(eW1n + 64 * 64, s * 32 + quad * 8, col, Vhi[s], Vlo[s]);
  }
  float b1 = nb1[col], b2 = nb2[col];

  __shared__ float Ta[128 * 17];   // [k=concat feat][node]
  __shared__ float Tt[64 * 17];    // [feat][node] layer-1 activations
  __shared__ float Th[64 * 17];    // [feat][node] new h
  __shared__ float Tu[64 * 17];
  __shared__ float Tv[64 * 17];

  for (int tile = blockIdx.x; tile < NODE_TILES; tile += gridDim.x) {
    int n0 = tile * 16;
#pragma unroll
    for (int e4 = 0; e4 < 4; ++e4) {
      int e = wv * 4 + e4;
      int n = min(n0 + e, N_NODES - 1);
      Ta[lane * 17 + e] = h[n * 64 + lane];
      Ta[(64 + lane) * 17 + e] = agg[n * 64 + lane];
    }
    __syncthreads();

    // layer 1: K=128
    f32x4 a1 = {};
#pragma unroll
    for (int s = 0; s < 4; ++s) {
      short8 ahi, alo;
      load_afrag(Ta, s, quad, n16, ahi, alo);
      a1 = mfma3(ahi, alo, W1hi[s], W1lo[s], a1);
    }
#pragma unroll
    for (int r = 0; r < 4; ++r)
      Tt[col * 17 + quad * 4 + r] = silu_f(a1[r] + b1);
    __syncthreads();

    // layer 2: K=64
    f32x4 a2 = {};
#pragma unroll
    for (int s = 0; s < 2; ++s) {
      short8 ahi, alo;
      load_afrag(Tt, s, quad, n16, ahi, alo);
      a2 = mfma3(ahi, alo, W2hi[s], W2lo[s], a2);
    }
#pragma unroll
    for (int r = 0; r < 4; ++r)
      Th[col * 17 + quad * 4 + r] = a2[r] + b2;
    __syncthreads();

    // next layer's pre: u/v from new h, K=64
    f32x4 aU = {}, aV = {};
#pragma unroll
    for (int s = 0; s < 2; ++s) {
      short8 ahi, alo;
      load_afrag(Th, s, quad, n16, ahi, alo);
      aU = mfma3(ahi, alo, Uhi[s], Ulo[s], aU);
      aV = mfma3(ahi, alo, Vhi[s], Vlo[s], aV);
    }
#pragma unroll
    for (int r = 0; r < 4; ++r) {
      Tu[col * 17 + quad * 4 + r] = aU[r];
      Tv[col * 17 + quad * 4 + r] = aV[r];
    }
    __syncthreads();

    // coalesced stores + agg zero
#pragma unroll
    for (int e4 = 0; e4 < 4; ++e4) {
      int e = wv * 4 + e4;
      int n = n0 + e;
      if (n < N_NODES) {
        h[n * 64 + lane] = Th[lane * 17 + e];
        u[n * 64 + lane] = Tu[lane * 17 + e];
        v[n * 64 + lane] = Tv[lane * 17 + e];
        agg[n * 64 + lane] = 0.f;
      }
    }
    __syncthreads();
  }
}

// ---------------------------------------------------------------------------
// Fused edge kernel over SORTED edges (verified round-3 version, unchanged).
// ---------------------------------------------------------------------------
__global__ __launch_bounds__(256) void k_edge(
    const float* __restrict__ u, const float* __restrict__ v,
    const int* __restrict__ srow, const int* __restrict__ scol,
    const float* __restrict__ sea,
    const float* __restrict__ wea, const float* __restrict__ eb1,
    const float* __restrict__ W2, const float* __restrict__ eb2,
    float* __restrict__ agg)
{
  const int lane = threadIdx.x & 63;
  const int wv = threadIdx.x >> 6;
  const int n16 = lane & 15;
  const int quad = lane >> 4;

  // B fragments (W2 columns), split hi/lo, resident in VGPRs.
  short8 Whi[2][4], Wlo[2][4];
#pragma unroll
  for (int s = 0; s < 2; ++s) {
#pragma unroll
    for (int nt = 0; nt < 4; ++nt) {
#pragma unroll
      for (int j = 0; j < 8; ++j) {
        float w2v = W2[(s * 32 + quad * 8 + j) * 64 + nt * 16 + n16];
        short hi = f2bf_s(w2v);
        Whi[s][nt][j] = hi;
        Wlo[s][nt][j] = f2bf_s(w2v - bf_s2f(hi));
      }
    }
  }
  float we = wea[lane];
  float b1v = eb1[lane];
  float b2v[4];
#pragma unroll
  for (int nt = 0; nt < 4; ++nt) b2v[nt] = eb2[nt * 16 + n16];

  __shared__ float Tl[4][64 * 17];   // [feat][edge], pad 17: <=2-way conflicts
  float* T = Tl[wv];

  const int wid = blockIdx.x * 4 + wv;
  const int tile0 = wid * TPW;
  const int tile1 = min(tile0 + TPW, EDGE_TILES);

  int cur_row = -1;
  bool first_atomic = true;
  float asum[4] = {0.f, 0.f, 0.f, 0.f};

  auto reduce_pick = [&](float a0, float a1, float a2, float a3) -> float {
    a0 += __shfl_xor(a0, 16); a0 += __shfl_xor(a0, 32);
    a1 += __shfl_xor(a1, 16); a1 += __shfl_xor(a1, 32);
    a2 += __shfl_xor(a2, 16); a2 += __shfl_xor(a2, 32);
    a3 += __shfl_xor(a3, 16); a3 += __shfl_xor(a3, 32);
    float o = a0;
    o = (quad == 1) ? a1 : o;
    o = (quad == 2) ? a2 : o;
    o = (quad == 3) ? a3 : o;
    return o;
  };

  for (int tile = tile0; tile < tile1; ++tile) {
    int e0 = tile * 16;
    int r16a = srow[e0 + n16];
    int c16a = scol[e0 + n16];
    float ea16 = sea[e0 + n16];

    // phase 1: 16 edges, lane = feature; wave-uniform indices via readlane.
#pragma unroll
    for (int e = 0; e < 16; ++e) {
      int r = __builtin_amdgcn_readlane(r16a, e);
      int c = __builtin_amdgcn_readlane(c16a, e);
      float ea = __int_as_float(__builtin_amdgcn_readlane(__float_as_int(ea16), e));
      float tt = u[r * 64 + lane] + v[c * 64 + lane] + ea * we + b1v;
      T[lane * 17 + e] = silu_f(tt);
    }
    __builtin_amdgcn_wave_barrier();

    f32x4 acc[4] = {};
#pragma unroll
    for (int s = 0; s < 2; ++s) {
      short8 ahi, alo;
#pragma unroll
      for (int j = 0; j < 8; ++j) {
        float tv = T[(s * 32 + quad * 8 + j) * 17 + n16];
        short hi = f2bf_s(tv);
        ahi[j] = hi;
        alo[j] = f2bf_s(tv - bf_s2f(hi));
      }
#pragma unroll
      for (int nt = 0; nt < 4; ++nt) {
        acc[nt] = __builtin_amdgcn_mfma_f32_16x16x32_bf16(ahi, Whi[s][nt], acc[nt], 0, 0, 0);
        acc[nt] = __builtin_amdgcn_mfma_f32_16x16x32_bf16(ahi, Wlo[s][nt], acc[nt], 0, 0, 0);
        acc[nt] = __builtin_amdgcn_mfma_f32_16x16x32_bf16(alo, Whi[s][nt], acc[nt], 0, 0, 0);
      }
    }
    __builtin_amdgcn_wave_barrier();

    // epilogue: silu, then running segmented reduce by row.
    float ev[4][4];
#pragma unroll
    for (int reg = 0; reg < 4; ++reg)
#pragma unroll
      for (int nt = 0; nt < 4; ++nt)
        ev[reg][nt] = silu_f(acc[nt][reg] + b2v[nt]);

    int rup = __shfl_up(r16a, 1);
    bool nf = (lane < 16) && ((lane == 0) ? (r16a != cur_row) : (r16a != rup));
    unsigned mask = (unsigned)(__ballot(nf) & 0xFFFFull);

    int s = 0;
    while (s < 16) {
      if ((mask >> s) & 1u) {
        if (cur_row >= 0) {
          float o = reduce_pick(asum[0], asum[1], asum[2], asum[3]);
          if (first_atomic) { unsafeAtomicAdd(&agg[cur_row * 64 + lane], o); first_atomic = false; }
          else agg[cur_row * 64 + lane] = o;
        }
        asum[0] = asum[1] = asum[2] = asum[3] = 0.f;
        cur_row = __shfl(r16a, s);
      }
      unsigned rem = mask & ~((2u << s) - 1u);
      int e = rem ? (__ffs(rem) - 1) : 16;
#pragma unroll
      for (int reg = 0; reg < 4; ++reg) {
        int m = quad * 4 + reg;
        bool in = (m >= s) && (m < e);
        asum[0] += in ? ev[reg][0] : 0.f;
        asum[1] += in ? ev[reg][1] : 0.f;
        asum[2] += in ? ev[reg][2] : 0.f;
        asum[3] += in ? ev[reg][3] : 0.f;
      }
      s = e;
    }
    __builtin_amdgcn_wave_barrier();
  }

  if (cur_row >= 0) {
    float o = reduce_pick(asum[0], asum[1], asum[2], asum[3]);
    unsafeAtomicAdd(&agg[cur_row * 64 + lane], o);
  }
}

// ---------------------------------------------------------------------------
// Final node MLP: out = silu(concat(h,agg) @ dnW1 + dnb1) @ dnW2 + dnb2, (N,4)
// ---------------------------------------------------------------------------
__global__ __launch_bounds__(256, 2) void k_node_final(
    const float* __restrict__ h, const float* __restrict__ agg,
    const float* __restrict__ dnW1, const float* __restrict__ dnb1,
    const float* __restrict__ dnW2, const float* __restrict__ dnb2,
    float* __restrict__ out)
{
  const int lane = threadIdx.x & 63;
  const int wv = threadIdx.x >> 6;
  float ar[64], br[64], wr[64];
#pragma unroll
  for (int k = 0; k < 64; ++k) {
    ar[k] = dnW1[k * 64 + lane];
    br[k] = dnW1[(64 + k) * 64 + lane];
    wr[k] = dnW2[k * 4 + (lane & 3)];
  }
  float b1v = dnb1[lane];
  float b2v = dnb2[lane & 3];
  __shared__ __align__(16) float hbuf[4][64];
  __shared__ __align__(16) float abuf[4][64];
  __shared__ __align__(16) float tbuf[4][64];
  float* hb = hbuf[wv]; float* ab = abuf[wv]; float* tb = tbuf[wv];
  const float4* hb4 = (const float4*)hb;
  const float4* ab4 = (const float4*)ab;
  const float4* tb4 = (const float4*)tb;

  int nw = gridDim.x * 4;
  int wid = blockIdx.x * 4 + wv;
  int per = (N_NODES + nw - 1) / nw;
  int n0 = wid * per, n1 = min(N_NODES, n0 + per);
  if (n0 >= n1) return;

  float hv = h[n0 * 64 + lane];
  float av = agg[n0 * 64 + lane];
  for (int n = n0; n < n1; ++n) {
    float hnext = 0.f, anext = 0.f;
    if (n + 1 < n1) {
      hnext = h[(n + 1) * 64 + lane];
      anext = agg[(n + 1) * 64 + lane];
    }
    hb[lane] = hv;
    ab[lane] = av;
    __builtin_amdgcn_wave_barrier();
    float t = b1v;
#pragma unroll
    for (int k4 = 0; k4 < 16; ++k4) {
      float4 hh = hb4[k4];
      float4 aa = ab4[k4];
      t += hh.x * ar[4 * k4 + 0] + aa.x * br[4 * k4 + 0];
      t += hh.y * ar[4 * k4 + 1] + aa.y * br[4 * k4 + 1];
      t += hh.z * ar[4 * k4 + 2] + aa.z * br[4 * k4 + 2];
      t += hh.w * ar[4 * k4 + 3] + aa.w * br[4 * k4 + 3];
    }
    t = silu_f(t);
    __builtin_amdgcn_wave_barrier();
    tb[lane] = t;
    __builtin_amdgcn_wave_barrier();
    float o = b2v;
#pragma unroll
    for (int k4 = 0; k4 < 16; ++k4) {
      float4 tt = tb4[k4];
      o += tt.x * wr[4 * k4 + 0];
      o += tt.y * wr[4 * k4 + 1];
      o += tt.z * wr[4 * k4 + 2];
      o += tt.w * wr[4 * k4 + 3];
    }
    if (lane < 4) out[n * 4 + lane] = o;
    __builtin_amdgcn_wave_barrier();
    hv = hnext; av = anext;
  }
}

extern "C" void kernel_launch(void* const* d_in, const int* in_sizes, int n_in,
                              void* d_out, int out_size, void* d_ws, size_t ws_size,
                              hipStream_t stream)
{
  const float* nodes = (const float*)d_in[0];
  const int*   edges = (const int*)d_in[1];
  const float* eatt  = (const float*)d_in[2];
  const float* W_emb = (const float*)d_in[3];
  const float* b_emb = (const float*)d_in[4];
  const float* Wg1   = (const float*)d_in[5];
  const float* bg1   = (const float*)d_in[6];
  const float* Wg2   = (const float*)d_in[7];
  const float* bg2   = (const float*)d_in[8];
  const float* eW1   = (const float*)d_in[9];
  const float* eb1   = (const float*)d_in[10];
  const float* eW2   = (const float*)d_in[11];
  const float* eb2   = (const float*)d_in[12];
  const float* nW1   = (const float*)d_in[13];
  const float* nb1   = (const float*)d_in[14];
  const float* nW2   = (const float*)d_in[15];
  const float* nb2   = (const float*)d_in[16];
  const float* deW1  = (const float*)d_in[17];
  const float* deb1  = (const float*)d_in[18];
  const float* deW2  = (const float*)d_in[19];
  const float* deb2  = (const float*)d_in[20];
  const float* dnW1  = (const float*)d_in[21];
  const float* dnb1  = (const float*)d_in[22];
  const float* dnW2  = (const float*)d_in[23];
  const float* dnb2  = (const float*)d_in[24];
  float* out = (float*)d_out;

  float* h   = (float*)d_ws;
  float* u   = h + N_NODES * 64;
  float* v   = u + N_NODES * 64;
  float* agg = v + N_NODES * 64;
  int* counts = (int*)(agg + N_NODES * 64);
  int* cursor = counts + N_NODES;
  int* bsum   = cursor + N_NODES;
  int* boffs  = bsum + 128;
  int* srow   = boffs + 128;
  int* scol   = srow + N_EDGES;
  float* sea  = (float*)(scol + N_EDGES);

  const int* rows = edges;
  const int* cols = edges + N_EDGES;

  // --- one-time edge sort by destination row (graph static across layers) ---
  hipMemsetAsync(counts, 0, N_NODES * sizeof(int), stream);
  k_hist<<<400, 256, 0, stream>>>(rows, counts);
  k_scanA<<<NB_SCAN, 256, 0, stream>>>(counts, bsum);
  k_scanB<<<1, 128, 0, stream>>>(bsum, boffs);
  k_scanC<<<NB_SCAN, 256, 0, stream>>>(counts, boffs, cursor);
  k_scatter<<<400, 256, 0, stream>>>(rows, cols, eatt, cursor, srow, scol, sea);

  k_embed<<<(N_NODES + 31) / 32, 256, 0, stream>>>(nodes, W_emb, b_emb, Wg1, bg1, Wg2, bg2, h);

  // layer-0 pre
  k_pre_mfma<<<NODE_BLOCKS, 256, 0, stream>>>(h, eW1, u, v, agg);

  for (int i = 0; i < 5; ++i) {
    const float* W1i = eW1 + i * 129 * 64;
    k_edge<<<EDGE_BLOCKS, 256, 0, stream>>>(u, v, srow, scol, sea, W1i + 128 * 64,
                                            eb1 + i * 64, eW2 + i * 64 * 64, eb2 + i * 64, agg);
    const float* eW1next = (i < 4) ? (eW1 + (i + 1) * 129 * 64) : deW1;
    k_postfused<<<NODE_BLOCKS, 256, 0, stream>>>(h, agg,
                                                 nW1 + i * 128 * 64, nb1 + i * 64,
                                                 nW2 + i * 64 * 64, nb2 + i * 64,
                                                 eW1next, u, v);
  }
  // decoder GCL edge pass
  k_edge<<<EDGE_BLOCKS, 256, 0, stream>>>(u, v, srow, scol, sea, deW1 + 128 * 64,
                                          deb1, deW2, deb2, agg);
  k_node_final<<<1024, 256, 0, stream>>>(h, agg, dnW1, dnb1, dnW2, dnb2, out);
}

// Round 5
// 517.806 us; speedup vs baseline: 2.2832x; 1.1966x over previous
//
#include <hip/hip_runtime.h>
#include <hip/hip_bf16.h>

#define N_NODES 25000
#define N_EDGES 400000
#define NB_SCAN ((N_NODES + 255) / 256)   // 98
#define EDGE_TILES (N_EDGES / 16)          // 25000
#define TPW 3                              // tiles per wave (edge kernel)
#define EDGE_WAVES ((EDGE_TILES + TPW - 1) / TPW)          // 8334
#define EDGE_BLOCKS ((EDGE_WAVES + 3) / 4)                 // 2084
#define NODE_TILES ((N_NODES + 15) / 16)   // 1563 -> one block per tile

typedef __attribute__((ext_vector_type(8))) short short8;
typedef __attribute__((ext_vector_type(4))) float f32x4;

// fast silu: v_rcp_f32 (<=1 ulp) instead of full-precision divide sequence
__device__ __forceinline__ float silu_f(float x) {
  return x * __builtin_amdgcn_rcpf(1.0f + __expf(-x));
}

__device__ __forceinline__ short f2bf_s(float x) {
  __hip_bfloat16 h = __float2bfloat16(x);
  return *reinterpret_cast<short*>(&h);
}
__device__ __forceinline__ float bf_s2f(short s) {
  __hip_bfloat16 h = *reinterpret_cast<__hip_bfloat16*>(&s);
  return __bfloat162float(h);
}

// --- shared MFMA helpers (layout identical to the verified k_edge path) ----
// A-frag from LDS tile T[k][m] (stride 17): A[m=n16][k=s*32+quad*8+j]
__device__ __forceinline__ void load_afrag(const float* T, int s, int quad, int n16,
                                           short8& ahi, short8& alo) {
#pragma unroll
  for (int j = 0; j < 8; ++j) {
    float tv = T[(s * 32 + quad * 8 + j) * 17 + n16];
    short hi = f2bf_s(tv);
    ahi[j] = hi;
    alo[j] = f2bf_s(tv - bf_s2f(hi));
  }
}
// B-frag from global W[k][n] (row-major, 64 cols): B[k=k0+j][n=col]
__device__ __forceinline__ void load_bfrag(const float* __restrict__ W, int k0, int col,
                                           short8& bhi, short8& blo) {
#pragma unroll
  for (int j = 0; j < 8; ++j) {
    float w = W[(k0 + j) * 64 + col];
    short hi = f2bf_s(w);
    bhi[j] = hi;
    blo[j] = f2bf_s(w - bf_s2f(hi));
  }
}
// split-bf16 3-product ~fp32 MFMA
__device__ __forceinline__ f32x4 mfma3(short8 ahi, short8 alo, short8 bhi, short8 blo,
                                       f32x4 acc) {
  acc = __builtin_amdgcn_mfma_f32_16x16x32_bf16(ahi, bhi, acc, 0, 0, 0);
  acc = __builtin_amdgcn_mfma_f32_16x16x32_bf16(ahi, blo, acc, 0, 0, 0);
  acc = __builtin_amdgcn_mfma_f32_16x16x32_bf16(alo, bhi, acc, 0, 0, 0);
  return acc;
}

// ---------------------------------------------------------------------------
// Edge preprocessing: counting sort by destination row (once per launch).
// ---------------------------------------------------------------------------
__global__ __launch_bounds__(256) void k_hist(const int* __restrict__ rows,
                                              int* __restrict__ counts)
{
  int stride = gridDim.x * blockDim.x;
  for (int e = blockIdx.x * blockDim.x + threadIdx.x; e < N_EDGES; e += stride)
    atomicAdd(&counts[rows[e]], 1);
}

__global__ __launch_bounds__(256) void k_scanA(const int* __restrict__ counts,
                                               int* __restrict__ bsum)
{
  __shared__ int sd[256];
  int t = threadIdx.x;
  int i = blockIdx.x * 256 + t;
  int x = (i < N_NODES) ? counts[i] : 0;
  sd[t] = x; __syncthreads();
  for (int d = 128; d > 0; d >>= 1) { if (t < d) sd[t] += sd[t + d]; __syncthreads(); }
  if (t == 0) bsum[blockIdx.x] = sd[0];
}

__global__ __launch_bounds__(128) void k_scanB(const int* __restrict__ bsum,
                                               int* __restrict__ boffs)
{
  __shared__ int buf[128];
  int t = threadIdx.x;
  int x = (t < NB_SCAN) ? bsum[t] : 0;
  buf[t] = x; __syncthreads();
  for (int d = 1; d < 128; d <<= 1) {
    int y = (t >= d) ? buf[t - d] : 0;
    __syncthreads();
    buf[t] += y;
    __syncthreads();
  }
  if (t < NB_SCAN) boffs[t] = buf[t] - x;   // exclusive block offsets
}

__global__ __launch_bounds__(256) void k_scanC(const int* __restrict__ counts,
                                               const int* __restrict__ boffs,
                                               int* __restrict__ cursor)
{
  __shared__ int buf[256];
  int t = threadIdx.x;
  int i = blockIdx.x * 256 + t;
  int x = (i < N_NODES) ? counts[i] : 0;
  buf[t] = x; __syncthreads();
  for (int d = 1; d < 256; d <<= 1) {
    int y = (t >= d) ? buf[t - d] : 0;
    __syncthreads();
    buf[t] += y;
    __syncthreads();
  }
  if (i < N_NODES) cursor[i] = boffs[blockIdx.x] + buf[t] - x;
}

__global__ __launch_bounds__(256) void k_scatter(
    const int* __restrict__ rows, const int* __restrict__ cols,
    const float* __restrict__ eatt, int* __restrict__ cursor,
    int* __restrict__ srow, int* __restrict__ scol, float* __restrict__ sea)
{
  int stride = gridDim.x * blockDim.x;
  for (int e = blockIdx.x * blockDim.x + threadIdx.x; e < N_EDGES; e += stride) {
    int r = rows[e];
    int pos = atomicAdd(&cursor[r], 1);
    srow[pos] = r;
    scol[pos] = cols[e];
    sea[pos] = eatt[e];
  }
}

// ---------------------------------------------------------------------------
// Fused embedding + layer-0 precompute (one 16-node tile per block):
//   feats128 = [base+s | base-s]  (group-equivariant embed, scalar per elem)
//   h   = silu(feats128 @ Wg1 + bg1) @ Wg2 + bg2
//   u   = h @ eW1_0[0:64] + eb1_0   (bias folded), v = h @ eW1_0[64:128]
//   agg <- 0
// ---------------------------------------------------------------------------
__global__ __launch_bounds__(256, 2) void k_embed_fused(
    const float* __restrict__ nodes,
    const float* __restrict__ W_emb, const float* __restrict__ b_emb,
    const float* __restrict__ Wg1, const float* __restrict__ bg1,
    const float* __restrict__ Wg2, const float* __restrict__ bg2,
    const float* __restrict__ eW1_0, const float* __restrict__ eb1_0,
    float* __restrict__ h, float* __restrict__ u, float* __restrict__ v,
    float* __restrict__ agg)
{
  const int lane = threadIdx.x & 63;
  const int wv = threadIdx.x >> 6;
  const int n16 = lane & 15;
  const int quad = lane >> 4;
  const int col = wv * 16 + n16;

  short8 W1hi[4], W1lo[4], W2hi[2], W2lo[2], Uhi[2], Ulo[2], Vhi[2], Vlo[2];
#pragma unroll
  for (int s = 0; s < 4; ++s)
    load_bfrag(Wg1, s * 32 + quad * 8, col, W1hi[s], W1lo[s]);
#pragma unroll
  for (int s = 0; s < 2; ++s) {
    load_bfrag(Wg2, s * 32 + quad * 8, col, W2hi[s], W2lo[s]);
    load_bfrag(eW1_0, s * 32 + quad * 8, col, Uhi[s], Ulo[s]);
    load_bfrag(eW1_0 + 64 * 64, s * 32 + quad * 8, col, Vhi[s], Vlo[s]);
  }
  float bg1v = bg1[col], bg2v = bg2[col], ebv = eb1_0[col];
  float w0 = W_emb[0 * 64 + lane], w1 = W_emb[1 * 64 + lane],
        w2 = W_emb[2 * 64 + lane], w3 = W_emb[3 * 64 + lane],
        w4 = W_emb[4 * 64 + lane];
  float bev = b_emb[lane];

  __shared__ float Ta[128 * 17];
  __shared__ float Tt[64 * 17];
  __shared__ float Th[64 * 17];
  __shared__ float Tu[64 * 17];
  __shared__ float Tv[64 * 17];

  int n0 = blockIdx.x * 16;
#pragma unroll
  for (int e4 = 0; e4 < 4; ++e4) {
    int e = wv * 4 + e4;
    int n = min(n0 + e, N_NODES - 1);
    float x0 = nodes[n * 5 + 0], x1 = nodes[n * 5 + 1],
          x2 = nodes[n * 5 + 2], x3 = nodes[n * 5 + 3],
          x4 = nodes[n * 5 + 4];
    float base = bev + x4 * w4;
    float sv = x0 * w0 + x1 * w1 + x2 * w2 + x3 * w3;
    Ta[lane * 17 + e] = base + sv;
    Ta[(64 + lane) * 17 + e] = base - sv;
  }
  __syncthreads();

  f32x4 a1 = {};
#pragma unroll
  for (int s = 0; s < 4; ++s) {
    short8 ahi, alo;
    load_afrag(Ta, s, quad, n16, ahi, alo);
    a1 = mfma3(ahi, alo, W1hi[s], W1lo[s], a1);
  }
#pragma unroll
  for (int r = 0; r < 4; ++r)
    Tt[col * 17 + quad * 4 + r] = silu_f(a1[r] + bg1v);
  __syncthreads();

  f32x4 a2 = {};
#pragma unroll
  for (int s = 0; s < 2; ++s) {
    short8 ahi, alo;
    load_afrag(Tt, s, quad, n16, ahi, alo);
    a2 = mfma3(ahi, alo, W2hi[s], W2lo[s], a2);
  }
#pragma unroll
  for (int r = 0; r < 4; ++r)
    Th[col * 17 + quad * 4 + r] = a2[r] + bg2v;
  __syncthreads();

  f32x4 aU = {}, aV = {};
#pragma unroll
  for (int s = 0; s < 2; ++s) {
    short8 ahi, alo;
    load_afrag(Th, s, quad, n16, ahi, alo);
    aU = mfma3(ahi, alo, Uhi[s], Ulo[s], aU);
    aV = mfma3(ahi, alo, Vhi[s], Vlo[s], aV);
  }
#pragma unroll
  for (int r = 0; r < 4; ++r) {
    Tu[col * 17 + quad * 4 + r] = aU[r] + ebv;
    Tv[col * 17 + quad * 4 + r] = aV[r];
  }
  __syncthreads();

#pragma unroll
  for (int e4 = 0; e4 < 4; ++e4) {
    int e = wv * 4 + e4;
    int n = n0 + e;
    if (n < N_NODES) {
      h[n * 64 + lane] = Th[lane * 17 + e];
      u[n * 64 + lane] = Tu[lane * 17 + e];
      v[n * 64 + lane] = Tv[lane * 17 + e];
      agg[n * 64 + lane] = 0.f;
    }
  }
}

// ---------------------------------------------------------------------------
// Fused MFMA node kernel (layer i post + layer i+1 pre), one tile per block:
//   t  = silu([h|agg] @ nW1 + nb1)   (K=128)
//   h' = t @ nW2 + nb2                (K=64)
//   u  = h' @ eW1n[0:64] + eb1n (bias folded), v = h' @ eW1n[64:128]; agg <- 0
// ---------------------------------------------------------------------------
__global__ __launch_bounds__(256, 2) void k_postfused(
    float* __restrict__ h, float* __restrict__ agg,
    const float* __restrict__ nW1, const float* __restrict__ nb1,
    const float* __restrict__ nW2, const float* __restrict__ nb2,
    const float* __restrict__ eW1n, const float* __restrict__ eb1n,
    float* __restrict__ u, float* __restrict__ v)
{
  const int lane = threadIdx.x & 63;
  const int wv = threadIdx.x >> 6;
  const int n16 = lane & 15;
  const int quad = lane >> 4;
  const int col = wv * 16 + n16;

  short8 W1hi[4], W1lo[4], W2hi[2], W2lo[2], Uhi[2], Ulo[2], Vhi[2], Vlo[2];
#pragma unroll
  for (int s = 0; s < 4; ++s)
    load_bfrag(nW1, s * 32 + quad * 8, col, W1hi[s], W1lo[s]);
#pragma unroll
  for (int s = 0; s < 2; ++s) {
    load_bfrag(nW2, s * 32 + quad * 8, col, W2hi[s], W2lo[s]);
    load_bfrag(eW1n, s * 32 + quad * 8, col, Uhi[s], Ulo[s]);
    load_bfrag(eW1n + 64 * 64, s * 32 + quad * 8, col, Vhi[s], Vlo[s]);
  }
  float b1 = nb1[col], b2 = nb2[col], ebv = eb1n[col];

  __shared__ float Ta[128 * 17];   // [k=concat feat][node]
  __shared__ float Tt[64 * 17];
  __shared__ float Th[64 * 17];
  __shared__ float Tu[64 * 17];
  __shared__ float Tv[64 * 17];

  int n0 = blockIdx.x * 16;
#pragma unroll
  for (int e4 = 0; e4 < 4; ++e4) {
    int e = wv * 4 + e4;
    int n = min(n0 + e, N_NODES - 1);
    Ta[lane * 17 + e] = h[n * 64 + lane];
    Ta[(64 + lane) * 17 + e] = agg[n * 64 + lane];
  }
  __syncthreads();

  // layer 1: K=128
  f32x4 a1 = {};
#pragma unroll
  for (int s = 0; s < 4; ++s) {
    short8 ahi, alo;
    load_afrag(Ta, s, quad, n16, ahi, alo);
    a1 = mfma3(ahi, alo, W1hi[s], W1lo[s], a1);
  }
#pragma unroll
  for (int r = 0; r < 4; ++r)
    Tt[col * 17 + quad * 4 + r] = silu_f(a1[r] + b1);
  __syncthreads();

  // layer 2: K=64
  f32x4 a2 = {};
#pragma unroll
  for (int s = 0; s < 2; ++s) {
    short8 ahi, alo;
    load_afrag(Tt, s, quad, n16, ahi, alo);
    a2 = mfma3(ahi, alo, W2hi[s], W2lo[s], a2);
  }
#pragma unroll
  for (int r = 0; r < 4; ++r)
    Th[col * 17 + quad * 4 + r] = a2[r] + b2;
  __syncthreads();

  // next layer's pre: u/v from new h, K=64
  f32x4 aU = {}, aV = {};
#pragma unroll
  for (int s = 0; s < 2; ++s) {
    short8 ahi, alo;
    load_afrag(Th, s, quad, n16, ahi, alo);
    aU = mfma3(ahi, alo, Uhi[s], Ulo[s], aU);
    aV = mfma3(ahi, alo, Vhi[s], Vlo[s], aV);
  }
#pragma unroll
  for (int r = 0; r < 4; ++r) {
    Tu[col * 17 + quad * 4 + r] = aU[r] + ebv;
    Tv[col * 17 + quad * 4 + r] = aV[r];
  }
  __syncthreads();

#pragma unroll
  for (int e4 = 0; e4 < 4; ++e4) {
    int e = wv * 4 + e4;
    int n = n0 + e;
    if (n < N_NODES) {
      h[n * 64 + lane] = Th[lane * 17 + e];
      u[n * 64 + lane] = Tu[lane * 17 + e];
      v[n * 64 + lane] = Tv[lane * 17 + e];
      agg[n * 64 + lane] = 0.f;
    }
  }
}

// ---------------------------------------------------------------------------
// Fused edge kernel over SORTED edges (verified round-3 structure).
// Round-5: eb1 folded into u upstream; v-gathers hoisted into registers;
// u-row gather cached behind a wave-uniform (SGPR) row-change branch --
// sorted rows mean ~2 distinct rows per 16-edge tile, not 16.
// ---------------------------------------------------------------------------
__global__ __launch_bounds__(256) void k_edge(
    const float* __restrict__ u, const float* __restrict__ v,
    const int* __restrict__ srow, const int* __restrict__ scol,
    const float* __restrict__ sea,
    const float* __restrict__ wea,
    const float* __restrict__ W2, const float* __restrict__ eb2,
    float* __restrict__ agg)
{
  const int lane = threadIdx.x & 63;
  const int wv = threadIdx.x >> 6;
  const int n16 = lane & 15;
  const int quad = lane >> 4;

  // B fragments (W2 columns), split hi/lo, resident in VGPRs.
  short8 Whi[2][4], Wlo[2][4];
#pragma unroll
  for (int s = 0; s < 2; ++s) {
#pragma unroll
    for (int nt = 0; nt < 4; ++nt) {
#pragma unroll
      for (int j = 0; j < 8; ++j) {
        float w2v = W2[(s * 32 + quad * 8 + j) * 64 + nt * 16 + n16];
        short hi = f2bf_s(w2v);
        Whi[s][nt][j] = hi;
        Wlo[s][nt][j] = f2bf_s(w2v - bf_s2f(hi));
      }
    }
  }
  float we = wea[lane];
  float b2v[4];
#pragma unroll
  for (int nt = 0; nt < 4; ++nt) b2v[nt] = eb2[nt * 16 + n16];

  __shared__ float Tl[4][64 * 17];   // [feat][edge], pad 17: <=2-way conflicts
  float* T = Tl[wv];

  const int wid = blockIdx.x * 4 + wv;
  const int tile0 = wid * TPW;
  const int tile1 = min(tile0 + TPW, EDGE_TILES);

  int cur_row = -1;
  bool first_atomic = true;
  float asum[4] = {0.f, 0.f, 0.f, 0.f};

  int r_prev = -1;        // wave-uniform (SGPR); u-row cache persists
  float uval = 0.f;       // across the wave's contiguous tiles

  auto reduce_pick = [&](float a0, float a1, float a2, float a3) -> float {
    a0 += __shfl_xor(a0, 16); a0 += __shfl_xor(a0, 32);
    a1 += __shfl_xor(a1, 16); a1 += __shfl_xor(a1, 32);
    a2 += __shfl_xor(a2, 16); a2 += __shfl_xor(a2, 32);
    a3 += __shfl_xor(a3, 16); a3 += __shfl_xor(a3, 32);
    float o = a0;
    o = (quad == 1) ? a1 : o;
    o = (quad == 2) ? a2 : o;
    o = (quad == 3) ? a3 : o;
    return o;
  };

  for (int tile = tile0; tile < tile1; ++tile) {
    int e0 = tile * 16;
    int r16a = srow[e0 + n16];
    int c16a = scol[e0 + n16];
    float ea16 = sea[e0 + n16];

    // hoist all 16 v-gathers so they stay in flight together
    float vv[16];
#pragma unroll
    for (int e = 0; e < 16; ++e) {
      int c = __builtin_amdgcn_readlane(c16a, e);
      vv[e] = v[c * 64 + lane];
    }

    // phase 1: 16 edges, lane = feature; u-row cached (rows sorted)
#pragma unroll
    for (int e = 0; e < 16; ++e) {
      int r = __builtin_amdgcn_readlane(r16a, e);
      if (r != r_prev) { uval = u[r * 64 + lane]; r_prev = r; }
      float ea = __int_as_float(__builtin_amdgcn_readlane(__float_as_int(ea16), e));
      float tt = uval + vv[e] + ea * we;
      T[lane * 17 + e] = silu_f(tt);
    }
    __builtin_amdgcn_wave_barrier();

    f32x4 acc[4] = {};
#pragma unroll
    for (int s = 0; s < 2; ++s) {
      short8 ahi, alo;
#pragma unroll
      for (int j = 0; j < 8; ++j) {
        float tv = T[(s * 32 + quad * 8 + j) * 17 + n16];
        short hi = f2bf_s(tv);
        ahi[j] = hi;
        alo[j] = f2bf_s(tv - bf_s2f(hi));
      }
#pragma unroll
      for (int nt = 0; nt < 4; ++nt) {
        acc[nt] = __builtin_amdgcn_mfma_f32_16x16x32_bf16(ahi, Whi[s][nt], acc[nt], 0, 0, 0);
        acc[nt] = __builtin_amdgcn_mfma_f32_16x16x32_bf16(ahi, Wlo[s][nt], acc[nt], 0, 0, 0);
        acc[nt] = __builtin_amdgcn_mfma_f32_16x16x32_bf16(alo, Whi[s][nt], acc[nt], 0, 0, 0);
      }
    }
    __builtin_amdgcn_wave_barrier();

    // epilogue: silu, then running segmented reduce by row.
    float ev[4][4];
#pragma unroll
    for (int reg = 0; reg < 4; ++reg)
#pragma unroll
      for (int nt = 0; nt < 4; ++nt)
        ev[reg][nt] = silu_f(acc[nt][reg] + b2v[nt]);

    int rup = __shfl_up(r16a, 1);
    bool nf = (lane < 16) && ((lane == 0) ? (r16a != cur_row) : (r16a != rup));
    unsigned mask = (unsigned)(__ballot(nf) & 0xFFFFull);

    int s = 0;
    while (s < 16) {
      if ((mask >> s) & 1u) {
        if (cur_row >= 0) {
          float o = reduce_pick(asum[0], asum[1], asum[2], asum[3]);
          if (first_atomic) { unsafeAtomicAdd(&agg[cur_row * 64 + lane], o); first_atomic = false; }
          else agg[cur_row * 64 + lane] = o;
        }
        asum[0] = asum[1] = asum[2] = asum[3] = 0.f;
        cur_row = __shfl(r16a, s);
      }
      unsigned rem = mask & ~((2u << s) - 1u);
      int e = rem ? (__ffs(rem) - 1) : 16;
#pragma unroll
      for (int reg = 0; reg < 4; ++reg) {
        int m = quad * 4 + reg;
        bool in = (m >= s) && (m < e);
        asum[0] += in ? ev[reg][0] : 0.f;
        asum[1] += in ? ev[reg][1] : 0.f;
        asum[2] += in ? ev[reg][2] : 0.f;
        asum[3] += in ? ev[reg][3] : 0.f;
      }
      s = e;
    }
    __builtin_amdgcn_wave_barrier();
  }

  if (cur_row >= 0) {
    float o = reduce_pick(asum[0], asum[1], asum[2], asum[3]);
    unsafeAtomicAdd(&agg[cur_row * 64 + lane], o);
  }
}

// ---------------------------------------------------------------------------
// Final node MLP (MFMA): out = silu([h|agg]@dnW1 + dnb1) @ dnW2 + dnb2, (N,4)
// Layer 1 via MFMA (K=128); layer 2 (K=64, N=4) as per-wave partial-k LDS dot.
// ---------------------------------------------------------------------------
__global__ __launch_bounds__(256, 2) void k_final_mfma(
    const float* __restrict__ h, const float* __restrict__ agg,
    const float* __restrict__ dnW1, const float* __restrict__ dnb1,
    const float* __restrict__ dnW2, const float* __restrict__ dnb2,
    float* __restrict__ out)
{
  const int lane = threadIdx.x & 63;
  const int wv = threadIdx.x >> 6;
  const int n16 = lane & 15;
  const int quad = lane >> 4;
  const int col = wv * 16 + n16;

  short8 W1hi[4], W1lo[4];
#pragma unroll
  for (int s = 0; s < 4; ++s)
    load_bfrag(dnW1, s * 32 + quad * 8, col, W1hi[s], W1lo[s]);
  float b1 = dnb1[col];

  __shared__ float Ta[128 * 17];
  __shared__ float Tt[64 * 17];
  __shared__ float W2s[256];
  __shared__ float Tp[4][64];

  W2s[threadIdx.x] = dnW2[threadIdx.x];   // 64x4 = 256 floats, 256 threads

  int n0 = blockIdx.x * 16;
#pragma unroll
  for (int e4 = 0; e4 < 4; ++e4) {
    int e = wv * 4 + e4;
    int n = min(n0 + e, N_NODES - 1);
    Ta[lane * 17 + e] = h[n * 64 + lane];
    Ta[(64 + lane) * 17 + e] = agg[n * 64 + lane];
  }
  __syncthreads();

  f32x4 a1 = {};
#pragma unroll
  for (int s = 0; s < 4; ++s) {
    short8 ahi, alo;
    load_afrag(Ta, s, quad, n16, ahi, alo);
    a1 = mfma3(ahi, alo, W1hi[s], W1lo[s], a1);
  }
#pragma unroll
  for (int r = 0; r < 4; ++r)
    Tt[col * 17 + quad * 4 + r] = silu_f(a1[r] + b1);
  __syncthreads();

  // layer 2: each lane handles (node m = lane>>2, out-col c = lane&3);
  // wave wv sums its k-range [wv*16, wv*16+16).
  int m = lane >> 2, c = lane & 3;
  float p = 0.f;
#pragma unroll
  for (int kk = 0; kk < 16; ++kk) {
    int k = wv * 16 + kk;
    p += Tt[k * 17 + m] * W2s[k * 4 + c];
  }
  Tp[wv][lane] = p;
  __syncthreads();

  if (threadIdx.x < 64) {
    int n = n0 + (threadIdx.x >> 2);
    if (n < N_NODES) {
      float o = Tp[0][threadIdx.x] + Tp[1][threadIdx.x] +
                Tp[2][threadIdx.x] + Tp[3][threadIdx.x] + dnb2[threadIdx.x & 3];
      out[n * 4 + (threadIdx.x & 3)] = o;
    }
  }
}

extern "C" void kernel_launch(void* const* d_in, const int* in_sizes, int n_in,
                              void* d_out, int out_size, void* d_ws, size_t ws_size,
                              hipStream_t stream)
{
  const float* nodes = (const float*)d_in[0];
  const int*   edges = (const int*)d_in[1];
  const float* eatt  = (const float*)d_in[2];
  const float* W_emb = (const float*)d_in[3];
  const float* b_emb = (const float*)d_in[4];
  const float* Wg1   = (const float*)d_in[5];
  const float* bg1   = (const float*)d_in[6];
  const float* Wg2   = (const float*)d_in[7];
  const float* bg2   = (const float*)d_in[8];
  const float* eW1   = (const float*)d_in[9];
  const float* eb1   = (const float*)d_in[10];
  const float* eW2   = (const float*)d_in[11];
  const float* eb2   = (const float*)d_in[12];
  const float* nW1   = (const float*)d_in[13];
  const float* nb1   = (const float*)d_in[14];
  const float* nW2   = (const float*)d_in[15];
  const float* nb2   = (const float*)d_in[16];
  const float* deW1  = (const float*)d_in[17];
  const float* deb1  = (const float*)d_in[18];
  const float* deW2  = (const float*)d_in[19];
  const float* deb2  = (const float*)d_in[20];
  const float* dnW1  = (const float*)d_in[21];
  const float* dnb1  = (const float*)d_in[22];
  const float* dnW2  = (const float*)d_in[23];
  const float* dnb2  = (const float*)d_in[24];
  float* out = (float*)d_out;

  float* h   = (float*)d_ws;
  float* u   = h + N_NODES * 64;
  float* v   = u + N_NODES * 64;
  float* agg = v + N_NODES * 64;
  int* counts = (int*)(agg + N_NODES * 64);
  int* cursor = counts + N_NODES;
  int* bsum   = cursor + N_NODES;
  int* boffs  = bsum + 128;
  int* srow   = boffs + 128;
  int* scol   = srow + N_EDGES;
  float* sea  = (float*)(scol + N_EDGES);

  const int* rows = edges;
  const int* cols = edges + N_EDGES;

  // --- one-time edge sort by destination row (graph static across layers) ---
  hipMemsetAsync(counts, 0, N_NODES * sizeof(int), stream);
  k_hist<<<400, 256, 0, stream>>>(rows, counts);
  k_scanA<<<NB_SCAN, 256, 0, stream>>>(counts, bsum);
  k_scanB<<<1, 128, 0, stream>>>(bsum, boffs);
  k_scanC<<<NB_SCAN, 256, 0, stream>>>(counts, boffs, cursor);
  k_scatter<<<400, 256, 0, stream>>>(rows, cols, eatt, cursor, srow, scol, sea);

  // fused embed + layer-0 u/v (eb1 of layer 0 folded into u)
  k_embed_fused<<<NODE_TILES, 256, 0, stream>>>(nodes, W_emb, b_emb, Wg1, bg1,
                                                Wg2, bg2, eW1, eb1, h, u, v, agg);

  for (int i = 0; i < 5; ++i) {
    const float* W1i = eW1 + i * 129 * 64;
    k_edge<<<EDGE_BLOCKS, 256, 0, stream>>>(u, v, srow, scol, sea, W1i + 128 * 64,
                                            eW2 + i * 64 * 64, eb2 + i * 64, agg);
    const float* eW1next = (i < 4) ? (eW1 + (i + 1) * 129 * 64) : deW1;
    const float* eb1next = (i < 4) ? (eb1 + (i + 1) * 64) : deb1;
    k_postfused<<<NODE_TILES, 256, 0, stream>>>(h, agg,
                                                nW1 + i * 128 * 64, nb1 + i * 64,
                                                nW2 + i * 64 * 64, nb2 + i * 64,
                                                eW1next, eb1next, u, v);
  }
  // decoder GCL edge pass
  k_edge<<<EDGE_BLOCKS, 256, 0, stream>>>(u, v, srow, scol, sea, deW1 + 128 * 64,
                                          deW2, deb2, agg);
  k_final_mfma<<<NODE_TILES, 256, 0, stream>>>(h, agg, dnW1, dnb1, dnW2, dnb2, out);
}

// Round 6
// 479.067 us; speedup vs baseline: 2.4679x; 1.0809x over previous
//
#include <hip/hip_runtime.h>
#include <hip/hip_bf16.h>

#define N_NODES 25000
#define N_EDGES 400000
#define NB_SCAN ((N_NODES + 255) / 256)   // 98
#define EDGE_TILES (N_EDGES / 16)          // 25000
#define TPW 2                              // tiles per wave (edge kernel)
#define EDGE_WAVES (EDGE_TILES / TPW)      // 12500 exact
#define EDGE_BLOCKS (EDGE_WAVES / 4)       // 3125 exact
#define NODE_TILES ((N_NODES + 15) / 16)   // 1563
#define NODE_BLOCKS2 ((NODE_TILES + 1) / 2) // 782 (2 tiles/block)

typedef __attribute__((ext_vector_type(8))) short short8;
typedef __attribute__((ext_vector_type(4))) float f32x4;

// fast silu: v_rcp_f32 (<=1 ulp) instead of full-precision divide sequence
__device__ __forceinline__ float silu_f(float x) {
  return x * __builtin_amdgcn_rcpf(1.0f + __expf(-x));
}

__device__ __forceinline__ short f2bf_s(float x) {
  __hip_bfloat16 h = __float2bfloat16(x);
  return *reinterpret_cast<short*>(&h);
}
__device__ __forceinline__ float bf_s2f(short s) {
  __hip_bfloat16 h = *reinterpret_cast<__hip_bfloat16*>(&s);
  return __bfloat162float(h);
}

// --- shared MFMA helpers (layout identical to the verified k_edge path) ----
// A-frag from LDS tile T[k][m] (stride 17): A[m=n16][k=s*32+quad*8+j]
__device__ __forceinline__ void load_afrag(const float* T, int s, int quad, int n16,
                                           short8& ahi, short8& alo) {
#pragma unroll
  for (int j = 0; j < 8; ++j) {
    float tv = T[(s * 32 + quad * 8 + j) * 17 + n16];
    short hi = f2bf_s(tv);
    ahi[j] = hi;
    alo[j] = f2bf_s(tv - bf_s2f(hi));
  }
}
// B-frag from global W[k][n] (row-major, 64 cols): B[k=k0+j][n=col]
__device__ __forceinline__ void load_bfrag(const float* __restrict__ W, int k0, int col,
                                           short8& bhi, short8& blo) {
#pragma unroll
  for (int j = 0; j < 8; ++j) {
    float w = W[(k0 + j) * 64 + col];
    short hi = f2bf_s(w);
    bhi[j] = hi;
    blo[j] = f2bf_s(w - bf_s2f(hi));
  }
}
// split-bf16 3-product ~fp32 MFMA
__device__ __forceinline__ f32x4 mfma3(short8 ahi, short8 alo, short8 bhi, short8 blo,
                                       f32x4 acc) {
  acc = __builtin_amdgcn_mfma_f32_16x16x32_bf16(ahi, bhi, acc, 0, 0, 0);
  acc = __builtin_amdgcn_mfma_f32_16x16x32_bf16(ahi, blo, acc, 0, 0, 0);
  acc = __builtin_amdgcn_mfma_f32_16x16x32_bf16(alo, bhi, acc, 0, 0, 0);
  return acc;
}

// ---------------------------------------------------------------------------
// Edge preprocessing: counting sort by destination row (once per launch).
// ---------------------------------------------------------------------------
__global__ __launch_bounds__(256) void k_hist(const int* __restrict__ rows,
                                              int* __restrict__ counts)
{
  int stride = gridDim.x * blockDim.x;
  for (int e = blockIdx.x * blockDim.x + threadIdx.x; e < N_EDGES; e += stride)
    atomicAdd(&counts[rows[e]], 1);
}

__global__ __launch_bounds__(256) void k_scanA(const int* __restrict__ counts,
                                               int* __restrict__ bsum)
{
  __shared__ int sd[256];
  int t = threadIdx.x;
  int i = blockIdx.x * 256 + t;
  int x = (i < N_NODES) ? counts[i] : 0;
  sd[t] = x; __syncthreads();
  for (int d = 128; d > 0; d >>= 1) { if (t < d) sd[t] += sd[t + d]; __syncthreads(); }
  if (t == 0) bsum[blockIdx.x] = sd[0];
}

__global__ __launch_bounds__(128) void k_scanB(const int* __restrict__ bsum,
                                               int* __restrict__ boffs)
{
  __shared__ int buf[128];
  int t = threadIdx.x;
  int x = (t < NB_SCAN) ? bsum[t] : 0;
  buf[t] = x; __syncthreads();
  for (int d = 1; d < 128; d <<= 1) {
    int y = (t >= d) ? buf[t - d] : 0;
    __syncthreads();
    buf[t] += y;
    __syncthreads();
  }
  if (t < NB_SCAN) boffs[t] = buf[t] - x;   // exclusive block offsets
}

__global__ __launch_bounds__(256) void k_scanC(const int* __restrict__ counts,
                                               const int* __restrict__ boffs,
                                               int* __restrict__ cursor)
{
  __shared__ int buf[256];
  int t = threadIdx.x;
  int i = blockIdx.x * 256 + t;
  int x = (i < N_NODES) ? counts[i] : 0;
  buf[t] = x; __syncthreads();
  for (int d = 1; d < 256; d <<= 1) {
    int y = (t >= d) ? buf[t - d] : 0;
    __syncthreads();
    buf[t] += y;
    __syncthreads();
  }
  if (i < N_NODES) cursor[i] = boffs[blockIdx.x] + buf[t] - x;
}

__global__ __launch_bounds__(256) void k_scatter(
    const int* __restrict__ rows, const int* __restrict__ cols,
    const float* __restrict__ eatt, int* __restrict__ cursor,
    int* __restrict__ srow, int* __restrict__ scol, float* __restrict__ sea)
{
  int stride = gridDim.x * blockDim.x;
  for (int e = blockIdx.x * blockDim.x + threadIdx.x; e < N_EDGES; e += stride) {
    int r = rows[e];
    int pos = atomicAdd(&cursor[r], 1);
    srow[pos] = r;
    scol[pos] = cols[e];
    sea[pos] = eatt[e];
  }
}

// ---------------------------------------------------------------------------
// W2 fragment prep: split each layer's eW2 (64x64 f32) into hi/lo bf16 in
// EXACT k_edge fragment order so k_edge loads short8 frags directly.
// short index: (((h*2+s)*4+nt)*4+quad)*128 + n16*8 + j ; 8192 shorts/layer.
// blockIdx.x = layer (0..4 = eW2[i], 5 = deW2).
// ---------------------------------------------------------------------------
__global__ __launch_bounds__(256) void k_w2prep(const float* __restrict__ eW2,
                                                const float* __restrict__ deW2,
                                                short* __restrict__ w2p)
{
  int layer = blockIdx.x;
  const float* src = (layer < 5) ? (eW2 + layer * 64 * 64) : deW2;
  short* dst = w2p + layer * 8192;
  for (int t = threadIdx.x; t < 4096; t += 256) {
    int j = t & 7, n16 = (t >> 3) & 15, quad = (t >> 7) & 3, nt = (t >> 9) & 3,
        s = (t >> 11) & 1;
    float val = src[(s * 32 + quad * 8 + j) * 64 + nt * 16 + n16];
    short hi = f2bf_s(val);
    short lo = f2bf_s(val - bf_s2f(hi));
    int base = ((s * 4 + nt) * 4 + quad) * 128 + n16 * 8 + j;
    dst[base] = hi;
    dst[base + 4096] = lo;
  }
}

// ---------------------------------------------------------------------------
// Fused embedding + layer-0 precompute (one 16-node tile per block).
// ---------------------------------------------------------------------------
__global__ __launch_bounds__(256, 2) void k_embed_fused(
    const float* __restrict__ nodes,
    const float* __restrict__ W_emb, const float* __restrict__ b_emb,
    const float* __restrict__ Wg1, const float* __restrict__ bg1,
    const float* __restrict__ Wg2, const float* __restrict__ bg2,
    const float* __restrict__ eW1_0, const float* __restrict__ eb1_0,
    float* __restrict__ h, float* __restrict__ u, float* __restrict__ v,
    float* __restrict__ agg)
{
  const int lane = threadIdx.x & 63;
  const int wv = threadIdx.x >> 6;
  const int n16 = lane & 15;
  const int quad = lane >> 4;
  const int col = wv * 16 + n16;

  short8 W1hi[4], W1lo[4], W2hi[2], W2lo[2], Uhi[2], Ulo[2], Vhi[2], Vlo[2];
#pragma unroll
  for (int s = 0; s < 4; ++s)
    load_bfrag(Wg1, s * 32 + quad * 8, col, W1hi[s], W1lo[s]);
#pragma unroll
  for (int s = 0; s < 2; ++s) {
    load_bfrag(Wg2, s * 32 + quad * 8, col, W2hi[s], W2lo[s]);
    load_bfrag(eW1_0, s * 32 + quad * 8, col, Uhi[s], Ulo[s]);
    load_bfrag(eW1_0 + 64 * 64, s * 32 + quad * 8, col, Vhi[s], Vlo[s]);
  }
  float bg1v = bg1[col], bg2v = bg2[col], ebv = eb1_0[col];
  float w0 = W_emb[0 * 64 + lane], w1 = W_emb[1 * 64 + lane],
        w2 = W_emb[2 * 64 + lane], w3 = W_emb[3 * 64 + lane],
        w4 = W_emb[4 * 64 + lane];
  float bev = b_emb[lane];

  __shared__ float Ta[128 * 17];
  __shared__ float Tt[64 * 17];
  __shared__ float Th[64 * 17];
  __shared__ float Tu[64 * 17];
  __shared__ float Tv[64 * 17];

  int n0 = blockIdx.x * 16;
#pragma unroll
  for (int e4 = 0; e4 < 4; ++e4) {
    int e = wv * 4 + e4;
    int n = min(n0 + e, N_NODES - 1);
    float x0 = nodes[n * 5 + 0], x1 = nodes[n * 5 + 1],
          x2 = nodes[n * 5 + 2], x3 = nodes[n * 5 + 3],
          x4 = nodes[n * 5 + 4];
    float base = bev + x4 * w4;
    float sv = x0 * w0 + x1 * w1 + x2 * w2 + x3 * w3;
    Ta[lane * 17 + e] = base + sv;
    Ta[(64 + lane) * 17 + e] = base - sv;
  }
  __syncthreads();

  f32x4 a1 = {};
#pragma unroll
  for (int s = 0; s < 4; ++s) {
    short8 ahi, alo;
    load_afrag(Ta, s, quad, n16, ahi, alo);
    a1 = mfma3(ahi, alo, W1hi[s], W1lo[s], a1);
  }
#pragma unroll
  for (int r = 0; r < 4; ++r)
    Tt[col * 17 + quad * 4 + r] = silu_f(a1[r] + bg1v);
  __syncthreads();

  f32x4 a2 = {};
#pragma unroll
  for (int s = 0; s < 2; ++s) {
    short8 ahi, alo;
    load_afrag(Tt, s, quad, n16, ahi, alo);
    a2 = mfma3(ahi, alo, W2hi[s], W2lo[s], a2);
  }
#pragma unroll
  for (int r = 0; r < 4; ++r)
    Th[col * 17 + quad * 4 + r] = a2[r] + bg2v;
  __syncthreads();

  f32x4 aU = {}, aV = {};
#pragma unroll
  for (int s = 0; s < 2; ++s) {
    short8 ahi, alo;
    load_afrag(Th, s, quad, n16, ahi, alo);
    aU = mfma3(ahi, alo, Uhi[s], Ulo[s], aU);
    aV = mfma3(ahi, alo, Vhi[s], Vlo[s], aV);
  }
#pragma unroll
  for (int r = 0; r < 4; ++r) {
    Tu[col * 17 + quad * 4 + r] = aU[r] + ebv;
    Tv[col * 17 + quad * 4 + r] = aV[r];
  }
  __syncthreads();

#pragma unroll
  for (int e4 = 0; e4 < 4; ++e4) {
    int e = wv * 4 + e4;
    int n = n0 + e;
    if (n < N_NODES) {
      h[n * 64 + lane] = Th[lane * 17 + e];
      u[n * 64 + lane] = Tu[lane * 17 + e];
      v[n * 64 + lane] = Tv[lane * 17 + e];
      agg[n * 64 + lane] = 0.f;
    }
  }
}

// ---------------------------------------------------------------------------
// Fused MFMA node kernel, TWO 16-node tiles per block, phase-interleaved with
// LDS aliasing (same 26KB/block as one tile -> 6 blocks/CU preserved).
// Per tile regions: LA[2176] (Ta; later Th in [0:1088) and Tu in [1088:2176)),
//                   LB[1088] (Tt; later Tv). Math identical to round 5.
// ---------------------------------------------------------------------------
__global__ __launch_bounds__(256, 2) void k_postfused(
    float* __restrict__ h, float* __restrict__ agg,
    const float* __restrict__ nW1, const float* __restrict__ nb1,
    const float* __restrict__ nW2, const float* __restrict__ nb2,
    const float* __restrict__ eW1n, const float* __restrict__ eb1n,
    float* __restrict__ u, float* __restrict__ v)
{
  const int lane = threadIdx.x & 63;
  const int wv = threadIdx.x >> 6;
  const int n16 = lane & 15;
  const int quad = lane >> 4;
  const int col = wv * 16 + n16;

  short8 W1hi[4], W1lo[4], W2hi[2], W2lo[2], Uhi[2], Ulo[2], Vhi[2], Vlo[2];
#pragma unroll
  for (int s = 0; s < 4; ++s)
    load_bfrag(nW1, s * 32 + quad * 8, col, W1hi[s], W1lo[s]);
#pragma unroll
  for (int s = 0; s < 2; ++s) {
    load_bfrag(nW2, s * 32 + quad * 8, col, W2hi[s], W2lo[s]);
    load_bfrag(eW1n, s * 32 + quad * 8, col, Uhi[s], Ulo[s]);
    load_bfrag(eW1n + 64 * 64, s * 32 + quad * 8, col, Vhi[s], Vlo[s]);
  }
  float b1 = nb1[col], b2 = nb2[col], ebv = eb1n[col];

  __shared__ float LA[2][128 * 17];   // Ta -> {Th | Tu}
  __shared__ float LB[2][64 * 17];    // Tt -> Tv

  int t0 = blockIdx.x * 2;            // tiles t0, t0+1 (t0+1 may exceed; clamped
                                      // loads + guarded stores make it safe)
  // P0: load [h|agg]
#pragma unroll
  for (int q = 0; q < 2; ++q) {
    int n0 = (t0 + q) * 16;
#pragma unroll
    for (int e4 = 0; e4 < 4; ++e4) {
      int e = wv * 4 + e4;
      int n = min(n0 + e, N_NODES - 1);
      LA[q][lane * 17 + e] = h[n * 64 + lane];
      LA[q][(64 + lane) * 17 + e] = agg[n * 64 + lane];
    }
  }
  __syncthreads();

  // P1: layer 1 (K=128) -> Tt in LB
  f32x4 a1[2] = {};
#pragma unroll
  for (int q = 0; q < 2; ++q)
#pragma unroll
    for (int s = 0; s < 4; ++s) {
      short8 ahi, alo;
      load_afrag(LA[q], s, quad, n16, ahi, alo);
      a1[q] = mfma3(ahi, alo, W1hi[s], W1lo[s], a1[q]);
    }
#pragma unroll
  for (int q = 0; q < 2; ++q)
#pragma unroll
    for (int r = 0; r < 4; ++r)
      LB[q][col * 17 + quad * 4 + r] = silu_f(a1[q][r] + b1);
  __syncthreads();

  // P2: layer 2 (K=64) -> Th into LA[0:1088) (Ta dead)
  f32x4 a2[2] = {};
#pragma unroll
  for (int q = 0; q < 2; ++q)
#pragma unroll
    for (int s = 0; s < 2; ++s) {
      short8 ahi, alo;
      load_afrag(LB[q], s, quad, n16, ahi, alo);
      a2[q] = mfma3(ahi, alo, W2hi[s], W2lo[s], a2[q]);
    }
#pragma unroll
  for (int q = 0; q < 2; ++q)
#pragma unroll
    for (int r = 0; r < 4; ++r)
      LA[q][col * 17 + quad * 4 + r] = a2[q][r] + b2;
  __syncthreads();

  // P3: next-layer pre (K=64): read Th (LA[0:1088)), write Tu (LA[1088:)),
  //     Tv (LB; Tt dead)
  f32x4 aU[2] = {}, aV[2] = {};
#pragma unroll
  for (int q = 0; q < 2; ++q)
#pragma unroll
    for (int s = 0; s < 2; ++s) {
      short8 ahi, alo;
      load_afrag(LA[q], s, quad, n16, ahi, alo);
      aU[q] = mfma3(ahi, alo, Uhi[s], Ulo[s], aU[q]);
      aV[q] = mfma3(ahi, alo, Vhi[s], Vlo[s], aV[q]);
    }
#pragma unroll
  for (int q = 0; q < 2; ++q)
#pragma unroll
    for (int r = 0; r < 4; ++r) {
      LA[q][1088 + col * 17 + quad * 4 + r] = aU[q][r] + ebv;
      LB[q][col * 17 + quad * 4 + r] = aV[q][r];
    }
  __syncthreads();

  // P4: coalesced stores + agg zero
#pragma unroll
  for (int q = 0; q < 2; ++q) {
    int n0 = (t0 + q) * 16;
#pragma unroll
    for (int e4 = 0; e4 < 4; ++e4) {
      int e = wv * 4 + e4;
      int n = n0 + e;
      if (n < N_NODES) {
        h[n * 64 + lane] = LA[q][lane * 17 + e];
        u[n * 64 + lane] = LA[q][1088 + lane * 17 + e];
        v[n * 64 + lane] = LB[q][lane * 17 + e];
        agg[n * 64 + lane] = 0.f;
      }
    }
  }
}

// ---------------------------------------------------------------------------
// Fused edge kernel over SORTED edges, TPW=2 tiles/wave, software-pipelined:
// tile-B index loads issued before tile-A compute; tile-B u/v gathers issued
// between A's MFMA and A's epilogue (latency hides under compute; counted
// vmcnt waits only -- no drains, no u-cache). W2 frags preloaded by k_w2prep.
// Phase math + segmented-reduction epilogue identical to verified round 3/5.
// ---------------------------------------------------------------------------
__global__ __launch_bounds__(256) void k_edge(
    const float* __restrict__ u, const float* __restrict__ v,
    const int* __restrict__ srow, const int* __restrict__ scol,
    const float* __restrict__ sea,
    const float* __restrict__ wea,
    const short* __restrict__ w2p, const float* __restrict__ eb2,
    float* __restrict__ agg)
{
  const int lane = threadIdx.x & 63;
  const int wv = threadIdx.x >> 6;
  const int n16 = lane & 15;
  const int quad = lane >> 4;

  // B fragments: direct coalesced short8 loads (prepped by k_w2prep)
  const short8* Wp8 = reinterpret_cast<const short8*>(w2p);
  short8 Whi[2][4], Wlo[2][4];
#pragma unroll
  for (int s = 0; s < 2; ++s)
#pragma unroll
    for (int nt = 0; nt < 4; ++nt) {
      Whi[s][nt] = Wp8[((s * 4 + nt) * 4 + quad) * 16 + n16];
      Wlo[s][nt] = Wp8[((s * 4 + nt) * 4 + quad) * 16 + n16 + 512];
    }
  float we = wea[lane];
  float b2v[4];
#pragma unroll
  for (int nt = 0; nt < 4; ++nt) b2v[nt] = eb2[nt * 16 + n16];

  __shared__ float Tl[4][64 * 17];   // [feat][edge], pad 17
  float* T = Tl[wv];

  const int wid = blockIdx.x * 4 + wv;
  const int tile0 = wid * TPW;       // exact: 12500 waves x 2 tiles = 25000

  int cur_row = -1;
  bool first_atomic = true;
  float asum[4] = {0.f, 0.f, 0.f, 0.f};

  auto reduce_pick = [&](float a0, float a1, float a2, float a3) -> float {
    a0 += __shfl_xor(a0, 16); a0 += __shfl_xor(a0, 32);
    a1 += __shfl_xor(a1, 16); a1 += __shfl_xor(a1, 32);
    a2 += __shfl_xor(a2, 16); a2 += __shfl_xor(a2, 32);
    a3 += __shfl_xor(a3, 16); a3 += __shfl_xor(a3, 32);
    float o = a0;
    o = (quad == 1) ? a1 : o;
    o = (quad == 2) ? a2 : o;
    o = (quad == 3) ? a3 : o;
    return o;
  };

  auto gather = [&](int r16a, int c16a, float (&uuT)[16], float (&vvT)[16]) {
#pragma unroll
    for (int e = 0; e < 16; ++e) {
      int r = __builtin_amdgcn_readlane(r16a, e);
      int c = __builtin_amdgcn_readlane(c16a, e);
      uuT[e] = u[r * 64 + lane];   // u has eb1 folded in
      vvT[e] = v[c * 64 + lane];
    }
  };

  auto phase1_mfma = [&](float ea16v, const float (&uuT)[16], const float (&vvT)[16],
                         f32x4 (&acc)[4]) {
#pragma unroll
    for (int e = 0; e < 16; ++e) {
      float ea = __int_as_float(__builtin_amdgcn_readlane(__float_as_int(ea16v), e));
      T[lane * 17 + e] = silu_f(uuT[e] + vvT[e] + ea * we);
    }
    __builtin_amdgcn_wave_barrier();
#pragma unroll
    for (int s = 0; s < 2; ++s) {
      short8 ahi, alo;
#pragma unroll
      for (int j = 0; j < 8; ++j) {
        float tv = T[(s * 32 + quad * 8 + j) * 17 + n16];
        short hi = f2bf_s(tv);
        ahi[j] = hi;
        alo[j] = f2bf_s(tv - bf_s2f(hi));
      }
#pragma unroll
      for (int nt = 0; nt < 4; ++nt) {
        acc[nt] = __builtin_amdgcn_mfma_f32_16x16x32_bf16(ahi, Whi[s][nt], acc[nt], 0, 0, 0);
        acc[nt] = __builtin_amdgcn_mfma_f32_16x16x32_bf16(ahi, Wlo[s][nt], acc[nt], 0, 0, 0);
        acc[nt] = __builtin_amdgcn_mfma_f32_16x16x32_bf16(alo, Whi[s][nt], acc[nt], 0, 0, 0);
      }
    }
    __builtin_amdgcn_wave_barrier();
  };

  auto epilogue = [&](int r16a, f32x4 (&acc)[4]) {
    float ev[4][4];
#pragma unroll
    for (int reg = 0; reg < 4; ++reg)
#pragma unroll
      for (int nt = 0; nt < 4; ++nt)
        ev[reg][nt] = silu_f(acc[nt][reg] + b2v[nt]);

    int rup = __shfl_up(r16a, 1);
    bool nf = (lane < 16) && ((lane == 0) ? (r16a != cur_row) : (r16a != rup));
    unsigned mask = (unsigned)(__ballot(nf) & 0xFFFFull);

    int s = 0;
    while (s < 16) {
      if ((mask >> s) & 1u) {
        if (cur_row >= 0) {
          float o = reduce_pick(asum[0], asum[1], asum[2], asum[3]);
          if (first_atomic) { unsafeAtomicAdd(&agg[cur_row * 64 + lane], o); first_atomic = false; }
          else agg[cur_row * 64 + lane] = o;
        }
        asum[0] = asum[1] = asum[2] = asum[3] = 0.f;
        cur_row = __shfl(r16a, s);
      }
      unsigned rem = mask & ~((2u << s) - 1u);
      int e = rem ? (__ffs(rem) - 1) : 16;
#pragma unroll
      for (int reg = 0; reg < 4; ++reg) {
        int m = quad * 4 + reg;
        bool in = (m >= s) && (m < e);
        asum[0] += in ? ev[reg][0] : 0.f;
        asum[1] += in ? ev[reg][1] : 0.f;
        asum[2] += in ? ev[reg][2] : 0.f;
        asum[3] += in ? ev[reg][3] : 0.f;
      }
      s = e;
    }
    __builtin_amdgcn_wave_barrier();
  };

  // ---- pipelined 2-tile schedule ----
  int e0 = tile0 * 16;
  int rA = srow[e0 + n16], cA = scol[e0 + n16];
  float eA = sea[e0 + n16];
  float uuA[16], vvA[16];
  gather(rA, cA, uuA, vvA);                 // tile-A gathers in flight

  int e1 = e0 + 16;                         // issue tile-B idx loads now;
  int rB = srow[e1 + n16], cB = scol[e1 + n16];  // they land during A compute
  float eB = sea[e1 + n16];

  f32x4 accA[4] = {};
  phase1_mfma(eA, uuA, vvA, accA);

  float uuB[16], vvB[16];
  gather(rB, cB, uuB, vvB);                 // B gathers hide under A epilogue

  epilogue(rA, accA);

  f32x4 accB[4] = {};
  phase1_mfma(eB, uuB, vvB, accB);
  epilogue(rB, accB);

  // final flush: row may continue into the next wave's range -> atomic
  if (cur_row >= 0) {
    float o = reduce_pick(asum[0], asum[1], asum[2], asum[3]);
    unsafeAtomicAdd(&agg[cur_row * 64 + lane], o);
  }
}

// ---------------------------------------------------------------------------
// Final node MLP (MFMA): out = silu([h|agg]@dnW1 + dnb1) @ dnW2 + dnb2, (N,4)
// ---------------------------------------------------------------------------
__global__ __launch_bounds__(256, 2) void k_final_mfma(
    const float* __restrict__ h, const float* __restrict__ agg,
    const float* __restrict__ dnW1, const float* __restrict__ dnb1,
    const float* __restrict__ dnW2, const float* __restrict__ dnb2,
    float* __restrict__ out)
{
  const int lane = threadIdx.x & 63;
  const int wv = threadIdx.x >> 6;
  const int n16 = lane & 15;
  const int quad = lane >> 4;
  const int col = wv * 16 + n16;

  short8 W1hi[4], W1lo[4];
#pragma unroll
  for (int s = 0; s < 4; ++s)
    load_bfrag(dnW1, s * 32 + quad * 8, col, W1hi[s], W1lo[s]);
  float b1 = dnb1[col];

  __shared__ float Ta[128 * 17];
  __shared__ float Tt[64 * 17];
  __shared__ float W2s[256];
  __shared__ float Tp[4][64];

  W2s[threadIdx.x] = dnW2[threadIdx.x];   // 64x4 = 256 floats

  int n0 = blockIdx.x * 16;
#pragma unroll
  for (int e4 = 0; e4 < 4; ++e4) {
    int e = wv * 4 + e4;
    int n = min(n0 + e, N_NODES - 1);
    Ta[lane * 17 + e] = h[n * 64 + lane];
    Ta[(64 + lane) * 17 + e] = agg[n * 64 + lane];
  }
  __syncthreads();

  f32x4 a1 = {};
#pragma unroll
  for (int s = 0; s < 4; ++s) {
    short8 ahi, alo;
    load_afrag(Ta, s, quad, n16, ahi, alo);
    a1 = mfma3(ahi, alo, W1hi[s], W1lo[s], a1);
  }
#pragma unroll
  for (int r = 0; r < 4; ++r)
    Tt[col * 17 + quad * 4 + r] = silu_f(a1[r] + b1);
  __syncthreads();

  int m = lane >> 2, c = lane & 3;
  float p = 0.f;
#pragma unroll
  for (int kk = 0; kk < 16; ++kk) {
    int k = wv * 16 + kk;
    p += Tt[k * 17 + m] * W2s[k * 4 + c];
  }
  Tp[wv][lane] = p;
  __syncthreads();

  if (threadIdx.x < 64) {
    int n = n0 + (threadIdx.x >> 2);
    if (n < N_NODES) {
      float o = Tp[0][threadIdx.x] + Tp[1][threadIdx.x] +
                Tp[2][threadIdx.x] + Tp[3][threadIdx.x] + dnb2[threadIdx.x & 3];
      out[n * 4 + (threadIdx.x & 3)] = o;
    }
  }
}

extern "C" void kernel_launch(void* const* d_in, const int* in_sizes, int n_in,
                              void* d_out, int out_size, void* d_ws, size_t ws_size,
                              hipStream_t stream)
{
  const float* nodes = (const float*)d_in[0];
  const int*   edges = (const int*)d_in[1];
  const float* eatt  = (const float*)d_in[2];
  const float* W_emb = (const float*)d_in[3];
  const float* b_emb = (const float*)d_in[4];
  const float* Wg1   = (const float*)d_in[5];
  const float* bg1   = (const float*)d_in[6];
  const float* Wg2   = (const float*)d_in[7];
  const float* bg2   = (const float*)d_in[8];
  const float* eW1   = (const float*)d_in[9];
  const float* eb1   = (const float*)d_in[10];
  const float* eW2   = (const float*)d_in[11];
  const float* eb2   = (const float*)d_in[12];
  const float* nW1   = (const float*)d_in[13];
  const float* nb1   = (const float*)d_in[14];
  const float* nW2   = (const float*)d_in[15];
  const float* nb2   = (const float*)d_in[16];
  const float* deW1  = (const float*)d_in[17];
  const float* deb1  = (const float*)d_in[18];
  const float* deW2  = (const float*)d_in[19];
  const float* deb2  = (const float*)d_in[20];
  const float* dnW1  = (const float*)d_in[21];
  const float* dnb1  = (const float*)d_in[22];
  const float* dnW2  = (const float*)d_in[23];
  const float* dnb2  = (const float*)d_in[24];
  float* out = (float*)d_out;

  float* h   = (float*)d_ws;
  float* u   = h + N_NODES * 64;
  float* v   = u + N_NODES * 64;
  float* agg = v + N_NODES * 64;
  int* counts = (int*)(agg + N_NODES * 64);
  int* cursor = counts + N_NODES;
  int* bsum   = cursor + N_NODES;
  int* boffs  = bsum + 128;
  int* srow   = boffs + 128;
  int* scol   = srow + N_EDGES;
  float* sea  = (float*)(scol + N_EDGES);
  short* w2p  = (short*)(sea + N_EDGES);   // 6 layers x 8192 shorts = 96 KB

  const int* rows = edges;
  const int* cols = edges + N_EDGES;

  // --- one-time preprocessing (graph static across layers) ---
  hipMemsetAsync(counts, 0, N_NODES * sizeof(int), stream);
  k_w2prep<<<6, 256, 0, stream>>>(eW2, deW2, w2p);
  k_hist<<<400, 256, 0, stream>>>(rows, counts);
  k_scanA<<<NB_SCAN, 256, 0, stream>>>(counts, bsum);
  k_scanB<<<1, 128, 0, stream>>>(bsum, boffs);
  k_scanC<<<NB_SCAN, 256, 0, stream>>>(counts, boffs, cursor);
  k_scatter<<<400, 256, 0, stream>>>(rows, cols, eatt, cursor, srow, scol, sea);

  // fused embed + layer-0 u/v (eb1 of layer 0 folded into u)
  k_embed_fused<<<NODE_TILES, 256, 0, stream>>>(nodes, W_emb, b_emb, Wg1, bg1,
                                                Wg2, bg2, eW1, eb1, h, u, v, agg);

  for (int i = 0; i < 5; ++i) {
    k_edge<<<EDGE_BLOCKS, 256, 0, stream>>>(u, v, srow, scol, sea,
                                            eW1 + i * 129 * 64 + 128 * 64,
                                            w2p + i * 8192, eb2 + i * 64, agg);
    const float* eW1next = (i < 4) ? (eW1 + (i + 1) * 129 * 64) : deW1;
    const float* eb1next = (i < 4) ? (eb1 + (i + 1) * 64) : deb1;
    k_postfused<<<NODE_BLOCKS2, 256, 0, stream>>>(h, agg,
                                                  nW1 + i * 128 * 64, nb1 + i * 64,
                                                  nW2 + i * 64 * 64, nb2 + i * 64,
                                                  eW1next, eb1next, u, v);
  }
  // decoder GCL edge pass
  k_edge<<<EDGE_BLOCKS, 256, 0, stream>>>(u, v, srow, scol, sea, deW1 + 128 * 64,
                                          w2p + 5 * 8192, deb2, agg);
  k_final_mfma<<<NODE_TILES, 256, 0, stream>>>(h, agg, dnW1, dnb1, dnW2, dnb2, out);
}